// Round 3
// baseline (2288.389 us; speedup 1.0000x reference)
//
#include <hip/hip_runtime.h>
#include <math.h>

typedef unsigned short u16;
typedef unsigned int u32;
typedef __attribute__((ext_vector_type(8))) __bf16 bf16x8;
typedef __attribute__((ext_vector_type(4))) float f32x4;
typedef __attribute__((ext_vector_type(8))) unsigned short ushort8v;
typedef __attribute__((ext_vector_type(4))) float float4v;
typedef __attribute__((ext_vector_type(4))) unsigned short u16x4;

typedef const __attribute__((address_space(1))) void gvoid_t;
typedef __attribute__((address_space(3))) void lvoid_t;

#define MFMA(a, b, c) __builtin_amdgcn_mfma_f32_16x16x32_bf16((a), (b), (c), 0, 0, 0)

// native RNE f32->bf16
__device__ __forceinline__ u16 f2bf(float f) {
  __bf16 h = (__bf16)f;
  return __builtin_bit_cast(u16, h);
}

// ---------------------------------------------------------------------------
// flash-attention staging: [rows][64] bf16 tiles (128B rows), XOR-swizzled
// source + swizzled reads (involution) -> conflict-free ds_read_b128.
// 4-wave (256 thread) version.
// ---------------------------------------------------------------------------
__device__ __forceinline__ void stage64(const u16* g, int ldg, u16* lds, int rows, int tid) {
  int w = tid >> 6, l = tid & 63;
  int lr = l >> 3;
  int cb = (l & 7) << 4;
  for (int it = 0; it < rows; it += 32) {
    int rbase = it + w * 8;
    int r = rbase + lr;
    int scb = cb ^ ((r & 7) << 4);
    const char* gp = (const char*)(g + (size_t)r * ldg) + scb;
    char* lp = (char*)lds + (size_t)rbase * 128;
    __builtin_amdgcn_global_load_lds((gvoid_t*)gp, (lvoid_t*)lp, 16, 0, 0);
  }
}

__device__ __forceinline__ bf16x8 ldsfrag(const u16* base, int row, int e0) {
  int boff = row * 128 + (((e0) << 1) ^ ((row & 7) << 4));
  return *(const bf16x8*)((const char*)base + boff);
}

// ---------------------------------------------------------------------------
// gemm256 staging: one K-slice (256 rows x 32 K, 64B rows, linear layout).
// 512 threads; dest is wave-uniform base + lane*16 (HW requirement).
// ---------------------------------------------------------------------------
__device__ __forceinline__ void stage_slice512(const u16* g, int ldg, char* dst, int tid) {
  int rr = tid >> 2, s = tid & 3;
  char* lp = dst + (tid >> 6) * 1024;   // wave-uniform
  #pragma unroll
  for (int i = 0; i < 2; ++i) {
    int row = i * 128 + rr;
    const char* gp = (const char*)g + (size_t)row * (ldg * 2) + s * 16;
    __builtin_amdgcn_global_load_lds((gvoid_t*)gp, (lvoid_t*)(lp + i * 8192), 16, 0, 0);
  }
}

// ---------------------------------------------------------------------------
// embed: x[b,s,:] = emb[tok[b,s],:] + pe[s,:]
// ---------------------------------------------------------------------------
__global__ void embed_kernel(const int* __restrict__ tok, const float* __restrict__ emb,
                             const float* __restrict__ pe, float* __restrict__ xf) {
  int row = blockIdx.x;
  int tid = threadIdx.x;              // 192
  int t = tok[row];
  int spos = row & 1023;
  float4v e = ((const float4v*)(emb + (size_t)t * 768))[tid];
  float4v p = ((const float4v*)(pe + (size_t)spos * 768))[tid];
  float4v r;
  r.x = e.x + p.x; r.y = e.y + p.y; r.z = e.z + p.z; r.w = e.w + p.w;
  ((float4v*)(xf + (size_t)row * 768))[tid] = r;
}

// ---------------------------------------------------------------------------
// layernorm row kernel
// ---------------------------------------------------------------------------
__global__ void ln_kernel(const float* __restrict__ x, const float* __restrict__ sc,
                          const float* __restrict__ bi, u16* __restrict__ out) {
  int row = blockIdx.x;
  int tid = threadIdx.x;  // 192
  float4v v = ((const float4v*)(x + (size_t)row * 768))[tid];
  float s = v.x + v.y + v.z + v.w;
  float s2 = v.x * v.x + v.y * v.y + v.z * v.z + v.w * v.w;
  #pragma unroll
  for (int off = 32; off >= 1; off >>= 1) {
    s += __shfl_down(s, off);
    s2 += __shfl_down(s2, off);
  }
  __shared__ float red[8];
  if ((tid & 63) == 0) { red[tid >> 6] = s; red[4 + (tid >> 6)] = s2; }
  __syncthreads();
  float S = red[0] + red[1] + red[2];
  float S2 = red[4] + red[5] + red[6];
  float m = S * (1.0f / 768.0f);
  float var = S2 * (1.0f / 768.0f) - m * m;
  float rs = rsqrtf(var + 1e-5f);
  float4v sv = ((const float4v*)sc)[tid];
  float4v bv = ((const float4v*)bi)[tid];
  u16x4 ov;
  ov.x = f2bf((v.x - m) * rs * sv.x + bv.x);
  ov.y = f2bf((v.y - m) * rs * sv.y + bv.y);
  ov.z = f2bf((v.z - m) * rs * sv.z + bv.z);
  ov.w = f2bf((v.w - m) * rs * sv.w + bv.w);
  *(u16x4*)(out + (size_t)row * 768 + tid * 4) = ov;
}

// ---------------------------------------------------------------------------
// weight converters: f32 [K][N] -> bf16 [N][K]
// ---------------------------------------------------------------------------
__global__ void convT_kernel(const float* __restrict__ src, u16* __restrict__ dst,
                             int N, int K, long long sz, long long dz) {
  src += (size_t)blockIdx.z * sz;
  dst += (size_t)blockIdx.z * dz;
  __shared__ float t[32][33];
  int n0 = blockIdx.x * 32, k0 = blockIdx.y * 32;
  int tid = threadIdx.x;
  int tx = tid & 31, ty = tid >> 5;
  for (int r = ty; r < 32; r += 8) t[r][tx] = src[(size_t)(k0 + r) * N + n0 + tx];
  __syncthreads();
  for (int r = ty; r < 32; r += 8) dst[(size_t)(n0 + r) * K + k0 + tx] = f2bf(t[tx][r]);
}

__global__ void convqkvT_kernel(const float* __restrict__ wq, const float* __restrict__ wk,
                                const float* __restrict__ wv, u16* __restrict__ dst,
                                long long wz, long long dz) {
  __shared__ float t[32][33];
  int n0 = blockIdx.x * 32, k0 = blockIdx.y * 32;
  int which = n0 / 768;
  int r0 = n0 % 768;
  int h = r0 >> 6, e0 = r0 & 63;
  const float* src = which == 0 ? wq : (which == 1 ? wk : wv);
  src += (size_t)blockIdx.z * wz;
  dst += (size_t)blockIdx.z * dz;
  int tid = threadIdx.x;
  int tx = tid & 31, ty = tid >> 5;
  for (int r = ty; r < 32; r += 8) t[r][tx] = src[(size_t)(h * 768 + k0 + r) * 64 + e0 + tx];
  __syncthreads();
  for (int r = ty; r < 32; r += 8) dst[(size_t)(n0 + r) * 768 + k0 + tx] = f2bf(t[tx][r]);
}

// ---------------------------------------------------------------------------
// v [bh][s][e] -> vt [bh][e][s]
// ---------------------------------------------------------------------------
__global__ void transpose_v_kernel(const u16* __restrict__ v, u16* __restrict__ vt) {
  __shared__ u16 t[64][72];
  int bh = blockIdx.x, sc = blockIdx.y;
  int tid = threadIdx.x;
  const u16* src = v + ((size_t)bh * 1024 + sc * 64) * 64;
  int sl = tid >> 2, e0 = (tid & 3) * 16;
  ushort8v a = *(const ushort8v*)(src + (size_t)sl * 64 + e0);
  ushort8v b = *(const ushort8v*)(src + (size_t)sl * 64 + e0 + 8);
  #pragma unroll
  for (int j = 0; j < 8; ++j) t[sl][e0 + j] = a[j];
  #pragma unroll
  for (int j = 0; j < 8; ++j) t[sl][e0 + 8 + j] = b[j];
  __syncthreads();
  int e = tid >> 2, s0 = (tid & 3) * 16;
  ushort8v o0, o1;
  #pragma unroll
  for (int j = 0; j < 8; ++j) o0[j] = t[s0 + j][e];
  #pragma unroll
  for (int j = 0; j < 8; ++j) o1[j] = t[s0 + 8 + j][e];
  u16* dst = vt + ((size_t)bh * 64 + e) * 1024 + sc * 64 + s0;
  *(ushort8v*)dst = o0;
  *(ushort8v*)(dst + 8) = o1;
}

// ---------------------------------------------------------------------------
// gemm256: C[M,N] = A[M,K]*Wt[N,K], 256x256 tile, 8 waves (2Mx4N, 128x64 each),
// K as 32-wide slices in a 4-slot LDS ring (128 KB dynamic), counted vmcnt(8),
// one raw s_barrier per phase, prefetch distance 3 slices.
// Race audit: phase ks stages slice ks+3 into slot (ks-1)&3, whose reads
// completed at phase ks-1's lgkmcnt(0), which precedes every wave's arrival
// at the phase-ks barrier. Reads of slot ks&3 complete before this phase's
// MFMAs, hence before the next phase's writes to it.
// MODE 0: QKV scatter  MODE 1: atomicAdd xf  MODE 2: gelu->bf16  MODE 3: atomicAdd xf (+bias z==0)
// ---------------------------------------------------------------------------
template <int MODE>
__global__ __launch_bounds__(512, 1) void gemm256(
    const u16* __restrict__ A, int lda, const u16* __restrict__ Wt, int ldb, int kChunk,
    float* __restrict__ xf, u16* __restrict__ outb, const float* __restrict__ bias,
    u16* __restrict__ qb, u16* __restrict__ kb, u16* __restrict__ vb) {
  extern __shared__ char lds[];
  int tid = threadIdx.x, lane = tid & 63, w = tid >> 6;
  int wm = w >> 2, wn = w & 3;
  int m0 = blockIdx.x * 256, n0 = blockIdx.y * 256;
  int kb0 = blockIdx.z * kChunk;
  int NK = kChunk >> 5;
  const u16* Ag = A + (size_t)m0 * lda + kb0;
  const u16* Bg = Wt + (size_t)n0 * ldb + kb0;
  f32x4 acc[8][4] = {};
  int lcb = (lane >> 4) << 4;   // byte col base {0,16,32,48}
  int lc = lane & 15;

  #pragma unroll
  for (int p = 0; p < 3; ++p) {
    stage_slice512(Ag + p * 32, lda, lds + (p & 3) * 32768, tid);
    stage_slice512(Bg + p * 32, ldb, lds + (p & 3) * 32768 + 16384, tid);
  }

  for (int ks = 0; ks < NK; ++ks) {
    int newer = NK - 1 - ks;
    if (newer >= 2)      asm volatile("s_waitcnt vmcnt(8)" ::: "memory");
    else if (newer == 1) asm volatile("s_waitcnt vmcnt(4)" ::: "memory");
    else                 asm volatile("s_waitcnt vmcnt(0)" ::: "memory");
    __builtin_amdgcn_sched_barrier(0);
    __builtin_amdgcn_s_barrier();
    __builtin_amdgcn_sched_barrier(0);

    char* sa = lds + (ks & 3) * 32768;
    char* sb = sa + 16384;
    bf16x8 af[8], bfr[4];
    #pragma unroll
    for (int mt = 0; mt < 8; ++mt) {
      int r = wm * 128 + mt * 16 + lc;
      af[mt] = *(const bf16x8*)(sa + r * 64 + lcb);
    }
    #pragma unroll
    for (int nt = 0; nt < 4; ++nt) {
      int r = wn * 64 + nt * 16 + lc;
      bfr[nt] = *(const bf16x8*)(sb + r * 64 + lcb);
    }
    if (ks + 3 < NK) {
      stage_slice512(Ag + (ks + 3) * 32, lda, lds + ((ks + 3) & 3) * 32768, tid);
      stage_slice512(Bg + (ks + 3) * 32, ldb, lds + ((ks + 3) & 3) * 32768 + 16384, tid);
    }
    asm volatile("s_waitcnt lgkmcnt(0)" ::: "memory");
    __builtin_amdgcn_sched_barrier(0);
    __builtin_amdgcn_s_setprio(1);
    #pragma unroll
    for (int mt = 0; mt < 8; ++mt)
      #pragma unroll
      for (int nt = 0; nt < 4; ++nt)
        acc[mt][nt] = MFMA(af[mt], bfr[nt], acc[mt][nt]);
    __builtin_amdgcn_s_setprio(0);
  }

  int rbase = m0 + wm * 128 + ((lane >> 4) << 2);
  int cbase = n0 + wn * 64 + lc;
  if constexpr (MODE == 0) {
    int which = n0 / 768;
    u16* dstb = which == 0 ? qb : (which == 1 ? kb : vb);
    int clocal = n0 - which * 768 + wn * 64 + lc;
    #pragma unroll
    for (int mt = 0; mt < 8; ++mt) {
      #pragma unroll
      for (int nt = 0; nt < 4; ++nt) {
        int rr = clocal + nt * 16;
        int h = rr >> 6, e = rr & 63;
        #pragma unroll
        for (int reg = 0; reg < 4; ++reg) {
          int row = rbase + mt * 16 + reg;
          int b = row >> 10, s = row & 1023;
          dstb[((size_t)(b * 12 + h) * 1024 + s) * 64 + e] = f2bf(acc[mt][nt][reg]);
        }
      }
    }
  } else if constexpr (MODE == 2) {
    #pragma unroll
    for (int mt = 0; mt < 8; ++mt) {
      #pragma unroll
      for (int nt = 0; nt < 4; ++nt) {
        int col = cbase + nt * 16;
        float bb = bias[col];
        #pragma unroll
        for (int reg = 0; reg < 4; ++reg) {
          int row = rbase + mt * 16 + reg;
          float t = acc[mt][nt][reg] + bb;
          float u = t * fmaf(t * t, 0.044715f, 1.0f);
          float ex = __builtin_amdgcn_exp2f(u * -2.3022156f);
          float g = t * __builtin_amdgcn_rcpf(1.0f + ex);
          outb[(size_t)row * 3072 + col] = f2bf(g);
        }
      }
    }
  } else {
    bool addb = (MODE == 3) && (blockIdx.z == 0);
    #pragma unroll
    for (int mt = 0; mt < 8; ++mt) {
      #pragma unroll
      for (int nt = 0; nt < 4; ++nt) {
        int col = cbase + nt * 16;
        float bb = addb ? bias[col] : 0.0f;
        #pragma unroll
        for (int reg = 0; reg < 4; ++reg) {
          int row = rbase + mt * 16 + reg;
          atomicAdd(&xf[(size_t)row * 768 + col], acc[mt][nt][reg] + bb);
        }
      }
    }
  }
}

// ---------------------------------------------------------------------------
// flash attention, fixed-shift softmax (exact shift-invariance), l = P@ones
// via MFMA. q,k: [bh][s][64] ; vt: [bh][e][s] ; o: [b,s, h*64+e]
// ---------------------------------------------------------------------------
__global__ __launch_bounds__(256) void flash64(
    const u16* __restrict__ q, const u16* __restrict__ k, const u16* __restrict__ vt,
    const int* __restrict__ kmask, u16* __restrict__ o) {
  __shared__ alignas(16) u16 Qs[64 * 64];
  __shared__ alignas(16) u16 Ks[64 * 64];
  __shared__ alignas(16) u16 Vs[64 * 64];
  __shared__ alignas(16) u16 Ps[64 * 64];
  int tid = threadIdx.x, lane = tid & 63, w = tid >> 6;
  int lc = lane & 15;
  int bh = blockIdx.x, q0 = blockIdx.y * 64;
  int b = bh / 12, h = bh % 12;

  stage64(q + ((size_t)bh * 1024 + q0) * 64, 64, Qs, 64, tid);
  __syncthreads();
  int qrow = w * 16 + lc;
  int e0 = (lane >> 4) * 8;
  bf16x8 aq0 = ldsfrag(Qs, qrow, e0);
  bf16x8 aq1 = ldsfrag(Qs, qrow, 32 + e0);

  bf16x8 ones;
  #pragma unroll
  for (int j = 0; j < 8; ++j) ones[j] = (__bf16)1.0f;

  f32x4 oacc[4] = {};
  f32x4 lacc = {};
  const float SCL = 0.125f * 1.44269504f;
  const float SH = -3.0f * 1.44269504f;
  int prow_base = w * 16 + ((lane >> 4) << 2);

  for (int kt = 0; kt < 16; ++kt) {
    __syncthreads();
    stage64(k + ((size_t)bh * 1024 + kt * 64) * 64, 64, Ks, 64, tid);
    stage64(vt + (size_t)bh * 64 * 1024 + kt * 64, 1024, Vs, 64, tid);
    __syncthreads();

    f32x4 sacc[4] = {};
    #pragma unroll
    for (int nt = 0; nt < 4; ++nt) {
      bf16x8 bk = ldsfrag(Ks, nt * 16 + lc, e0);
      sacc[nt] = MFMA(aq0, bk, sacc[nt]);
    }
    #pragma unroll
    for (int nt = 0; nt < 4; ++nt) {
      bf16x8 bk = ldsfrag(Ks, nt * 16 + lc, 32 + e0);
      sacc[nt] = MFMA(aq1, bk, sacc[nt]);
    }

    #pragma unroll
    for (int nt = 0; nt < 4; ++nt) {
      int c = nt * 16 + lc;
      float mk = kmask[b * 1024 + kt * 64 + c] ? SH : -1e30f;
      #pragma unroll
      for (int r = 0; r < 4; ++r) {
        float p = __builtin_amdgcn_exp2f(fmaf(sacc[nt][r], SCL, mk));
        int prow = prow_base + r;
        int boff = prow * 128 + ((c << 1) ^ ((prow & 7) << 4));
        *(u16*)((char*)Ps + boff) = f2bf(p);
      }
    }

    bf16x8 ap0 = ldsfrag(Ps, qrow, e0);
    bf16x8 ap1 = ldsfrag(Ps, qrow, 32 + e0);
    lacc = MFMA(ap0, ones, lacc);
    lacc = MFMA(ap1, ones, lacc);
    #pragma unroll
    for (int et = 0; et < 4; ++et) {
      bf16x8 bv = ldsfrag(Vs, et * 16 + lc, e0);
      oacc[et] = MFMA(ap0, bv, oacc[et]);
    }
    #pragma unroll
    for (int et = 0; et < 4; ++et) {
      bf16x8 bv = ldsfrag(Vs, et * 16 + lc, 32 + e0);
      oacc[et] = MFMA(ap1, bv, oacc[et]);
    }
  }

  float rl[4];
  #pragma unroll
  for (int r = 0; r < 4; ++r) rl[r] = __builtin_amdgcn_rcpf(lacc[r]);
  int orow_base = q0 + prow_base;
  #pragma unroll
  for (int et = 0; et < 4; ++et) {
    int e = et * 16 + lc;
    #pragma unroll
    for (int r = 0; r < 4; ++r) {
      int row = orow_base + r;
      o[((size_t)(b * 1024 + row)) * 768 + h * 64 + e] = f2bf(oacc[et][r] * rl[r]);
    }
  }
}

__global__ void copy_kernel(const float* __restrict__ src, float* __restrict__ dst) {
  size_t i = (size_t)blockIdx.x * blockDim.x + threadIdx.x;
  ((float4v*)dst)[i] = ((const float4v*)src)[i];
}

// ---------------------------------------------------------------------------
extern "C" void kernel_launch(void* const* d_in, const int* in_sizes, int n_in,
                              void* d_out, int out_size, void* d_ws, size_t ws_size,
                              hipStream_t stream) {
  const int* tokens = (const int*)d_in[0];
  const int* kmask = (const int*)d_in[1];
  const float* emb = (const float*)d_in[2];
  const float* pe = (const float*)d_in[3];
  const float* ln1_s = (const float*)d_in[4];
  const float* ln1_b = (const float*)d_in[5];
  const float* wq = (const float*)d_in[6];
  const float* wk = (const float*)d_in[7];
  const float* wv = (const float*)d_in[8];
  const float* wo = (const float*)d_in[9];
  const float* ln2_s = (const float*)d_in[10];
  const float* ln2_b = (const float*)d_in[11];
  const float* w1 = (const float*)d_in[12];
  const float* b1 = (const float*)d_in[13];
  const float* w2 = (const float*)d_in[14];
  const float* b2 = (const float*)d_in[15];

  // opt-in to 128 KB dynamic LDS for gemm256 (sticky per-function; first call
  // happens outside graph capture; errors ignored)
  (void)hipFuncSetAttribute((const void*)gemm256<0>, hipFuncAttributeMaxDynamicSharedMemorySize, 131072);
  (void)hipFuncSetAttribute((const void*)gemm256<1>, hipFuncAttributeMaxDynamicSharedMemorySize, 131072);
  (void)hipFuncSetAttribute((const void*)gemm256<2>, hipFuncAttributeMaxDynamicSharedMemorySize, 131072);
  (void)hipFuncSetAttribute((const void*)gemm256<3>, hipFuncAttributeMaxDynamicSharedMemorySize, 131072);

  char* ws = (char*)d_ws;
  float* xf = (float*)ws;                       // 8192*768*4
  u16* xn   = (u16*)(ws + 25165824);
  u16* qb   = (u16*)(ws + 37748736);
  u16* kb   = (u16*)(ws + 50331648);
  u16* vb   = (u16*)(ws + 62914560);
  u16* vtb  = (u16*)(ws + 75497472);
  u16* ob   = (u16*)(ws + 88080384);
  u16* ffh  = (u16*)(ws + 100663296);           // 8192*3072*2

  const size_t SZ_QKV = (size_t)2304 * 768;
  const size_t SZ_O   = (size_t)768 * 768;
  const size_t SZ_F1  = (size_t)3072 * 768;
  const size_t SZ_F2  = (size_t)768 * 3072;
  const size_t NEED = 150994944 + 2 * 6 * (SZ_QKV + SZ_O + SZ_F1 + SZ_F2);
  bool pre = ws_size >= NEED;
  int nz = pre ? 6 : 1;
  u16* wqkvt = (u16*)(ws + 150994944);
  u16* wot   = wqkvt + (size_t)nz * SZ_QKV;
  u16* w1t   = wot + (size_t)nz * SZ_O;
  u16* w2t   = w1t + (size_t)nz * SZ_F1;

  embed_kernel<<<8192, 192, 0, stream>>>(tokens, emb, pe, xf);

  if (pre) {
    convqkvT_kernel<<<dim3(72, 24, 6), 256, 0, stream>>>(wq, wk, wv, wqkvt, 589824LL, (long long)SZ_QKV);
    convT_kernel<<<dim3(24, 24, 6), 256, 0, stream>>>(wo, wot, 768, 768, 589824LL, (long long)SZ_O);
    convT_kernel<<<dim3(96, 24, 6), 256, 0, stream>>>(w1, w1t, 3072, 768, 2359296LL, (long long)SZ_F1);
    convT_kernel<<<dim3(24, 96, 6), 256, 0, stream>>>(w2, w2t, 768, 3072, 2359296LL, (long long)SZ_F2);
  }

  for (int l = 0; l < 6; ++l) {
    size_t woff_qkv = (size_t)l * 12 * 768 * 64;
    size_t woff_o = (size_t)l * 768 * 768;
    size_t woff_ff = (size_t)l * 768 * 3072;
    const u16* wt_qkv_l = wqkvt + (pre ? (size_t)l * SZ_QKV : 0);
    const u16* wt_o_l   = wot   + (pre ? (size_t)l * SZ_O   : 0);
    const u16* wt_1_l   = w1t   + (pre ? (size_t)l * SZ_F1  : 0);
    const u16* wt_2_l   = w2t   + (pre ? (size_t)l * SZ_F2  : 0);

    if (!pre) {
      convqkvT_kernel<<<dim3(72, 24, 1), 256, 0, stream>>>(wq + woff_qkv, wk + woff_qkv, wv + woff_qkv, (u16*)wt_qkv_l, 0LL, 0LL);
      convT_kernel<<<dim3(24, 24, 1), 256, 0, stream>>>(wo + woff_o, (u16*)wt_o_l, 768, 768, 0LL, 0LL);
      convT_kernel<<<dim3(96, 24, 1), 256, 0, stream>>>(w1 + woff_ff, (u16*)wt_1_l, 3072, 768, 0LL, 0LL);
      convT_kernel<<<dim3(24, 96, 1), 256, 0, stream>>>(w2 + woff_ff, (u16*)wt_2_l, 768, 3072, 0LL, 0LL);
    }

    ln_kernel<<<8192, 192, 0, stream>>>(xf, ln1_s + l * 768, ln1_b + l * 768, xn);
    gemm256<0><<<dim3(32, 9, 1), 512, 131072, stream>>>(xn, 768, wt_qkv_l, 768, 768, nullptr, nullptr, nullptr, qb, kb, vb);
    transpose_v_kernel<<<dim3(96, 16), 256, 0, stream>>>(vb, vtb);
    flash64<<<dim3(96, 16), 256, 0, stream>>>(qb, kb, vtb, kmask, ob);
    gemm256<1><<<dim3(32, 3, 3), 512, 131072, stream>>>(ob, 768, wt_o_l, 768, 256, xf, nullptr, nullptr, nullptr, nullptr, nullptr);
    ln_kernel<<<8192, 192, 0, stream>>>(xf, ln2_s + l * 768, ln2_b + l * 768, xn);
    gemm256<2><<<dim3(32, 12, 1), 512, 131072, stream>>>(xn, 768, wt_1_l, 768, 768, nullptr, ffh, b1 + l * 3072, nullptr, nullptr, nullptr);
    gemm256<3><<<dim3(32, 3, 3), 512, 131072, stream>>>(ffh, 3072, wt_2_l, 3072, 1024, xf, nullptr, b2 + l * 768, nullptr, nullptr, nullptr);
  }

  copy_kernel<<<6144, 256, 0, stream>>>(xf, (float*)d_out);
}

// Round 4
// 2258.249 us; speedup vs baseline: 1.0133x; 1.0133x over previous
//
#include <hip/hip_runtime.h>
#include <math.h>

typedef unsigned short u16;
typedef unsigned int u32;
typedef __attribute__((ext_vector_type(8))) __bf16 bf16x8;
typedef __attribute__((ext_vector_type(4))) float f32x4;
typedef __attribute__((ext_vector_type(8))) unsigned short ushort8v;
typedef __attribute__((ext_vector_type(4))) float float4v;
typedef __attribute__((ext_vector_type(4))) unsigned short u16x4;

typedef const __attribute__((address_space(1))) void gvoid_t;
typedef __attribute__((address_space(3))) void lvoid_t;

#define MFMA(a, b, c) __builtin_amdgcn_mfma_f32_16x16x32_bf16((a), (b), (c), 0, 0, 0)

// native RNE f32->bf16
__device__ __forceinline__ u16 f2bf(float f) {
  __bf16 h = (__bf16)f;
  return __builtin_bit_cast(u16, h);
}

// ---------------------------------------------------------------------------
// flash-attention staging: [rows][64] bf16 tiles (128B rows), XOR-swizzled
// source + swizzled reads (involution, (r&7)<<4) -> conflict-free ds_read_b128.
// 4-wave (256 thread) version. (proven: 0 conflicts in rounds 1-2)
// ---------------------------------------------------------------------------
__device__ __forceinline__ void stage64(const u16* g, int ldg, u16* lds, int rows, int tid) {
  int w = tid >> 6, l = tid & 63;
  int lr = l >> 3;
  int cb = (l & 7) << 4;
  for (int it = 0; it < rows; it += 32) {
    int rbase = it + w * 8;
    int r = rbase + lr;
    int scb = cb ^ ((r & 7) << 4);
    const char* gp = (const char*)(g + (size_t)r * ldg) + scb;
    char* lp = (char*)lds + (size_t)rbase * 128;
    __builtin_amdgcn_global_load_lds((gvoid_t*)gp, (lvoid_t*)lp, 16, 0, 0);
  }
}

__device__ __forceinline__ bf16x8 ldsfrag(const u16* base, int row, int e0) {
  int boff = row * 128 + (((e0) << 1) ^ ((row & 7) << 4));
  return *(const bf16x8*)((const char*)base + boff);
}

// ---------------------------------------------------------------------------
// gemm256 staging: one K-slice (256 rows x 32 K, 64B rows). Dest is linear
// (wave-uniform base + lane*16, HW requirement); SOURCE 16B-slot is XOR'd
// with ((row>>1)&3) and reads apply the same XOR -> bank-quad map is
// bijective mod 8 -> 2-way (free) instead of 8-way conflicts.
// 512 threads: 2 loads/thread per operand slice.
// ---------------------------------------------------------------------------
__device__ __forceinline__ void stage_slice(const u16* g, int ldg, char* dst, int tid) {
  int lane = tid & 63, w = tid >> 6;
  #pragma unroll
  for (int i = 0; i < 2; ++i) {
    int row = i * 128 + w * 16 + (lane >> 2);
    int se = (lane & 3) ^ ((row >> 1) & 3);
    const char* gp = (const char*)(g + (size_t)row * ldg) + (se << 4);
    char* lp = dst + i * 8192 + w * 1024;   // + lane*16 (implicit, linear)
    __builtin_amdgcn_global_load_lds((gvoid_t*)gp, (lvoid_t*)lp, 16, 0, 0);
  }
}

// read 16B at (row r, 16B-slot t) from a swizzled slice
__device__ __forceinline__ bf16x8 ringfrag(const char* base, int r, int t) {
  return *(const bf16x8*)(base + r * 64 + ((t ^ ((r >> 1) & 3)) << 4));
}

// ---------------------------------------------------------------------------
// embed: x[b,s,:] = emb[tok[b,s],:] + pe[s,:]
// ---------------------------------------------------------------------------
__global__ void embed_kernel(const int* __restrict__ tok, const float* __restrict__ emb,
                             const float* __restrict__ pe, float* __restrict__ xf) {
  int row = blockIdx.x;
  int tid = threadIdx.x;              // 192
  int t = tok[row];
  int spos = row & 1023;
  float4v e = ((const float4v*)(emb + (size_t)t * 768))[tid];
  float4v p = ((const float4v*)(pe + (size_t)spos * 768))[tid];
  float4v r;
  r.x = e.x + p.x; r.y = e.y + p.y; r.z = e.z + p.z; r.w = e.w + p.w;
  ((float4v*)(xf + (size_t)row * 768))[tid] = r;
}

// ---------------------------------------------------------------------------
// layernorm row kernel
// ---------------------------------------------------------------------------
__global__ void ln_kernel(const float* __restrict__ x, const float* __restrict__ sc,
                          const float* __restrict__ bi, u16* __restrict__ out) {
  int row = blockIdx.x;
  int tid = threadIdx.x;  // 192
  float4v v = ((const float4v*)(x + (size_t)row * 768))[tid];
  float s = v.x + v.y + v.z + v.w;
  float s2 = v.x * v.x + v.y * v.y + v.z * v.z + v.w * v.w;
  #pragma unroll
  for (int off = 32; off >= 1; off >>= 1) {
    s += __shfl_down(s, off);
    s2 += __shfl_down(s2, off);
  }
  __shared__ float red[8];
  if ((tid & 63) == 0) { red[tid >> 6] = s; red[4 + (tid >> 6)] = s2; }
  __syncthreads();
  float S = red[0] + red[1] + red[2];
  float S2 = red[4] + red[5] + red[6];
  float m = S * (1.0f / 768.0f);
  float var = S2 * (1.0f / 768.0f) - m * m;
  float rs = rsqrtf(var + 1e-5f);
  float4v sv = ((const float4v*)sc)[tid];
  float4v bv = ((const float4v*)bi)[tid];
  u16x4 ov;
  ov.x = f2bf((v.x - m) * rs * sv.x + bv.x);
  ov.y = f2bf((v.y - m) * rs * sv.y + bv.y);
  ov.z = f2bf((v.z - m) * rs * sv.z + bv.z);
  ov.w = f2bf((v.w - m) * rs * sv.w + bv.w);
  *(u16x4*)(out + (size_t)row * 768 + tid * 4) = ov;
}

// ---------------------------------------------------------------------------
// weight converters: f32 [K][N] -> bf16 [N][K]
// ---------------------------------------------------------------------------
__global__ void convT_kernel(const float* __restrict__ src, u16* __restrict__ dst,
                             int N, int K, long long sz, long long dz) {
  src += (size_t)blockIdx.z * sz;
  dst += (size_t)blockIdx.z * dz;
  __shared__ float t[32][33];
  int n0 = blockIdx.x * 32, k0 = blockIdx.y * 32;
  int tid = threadIdx.x;
  int tx = tid & 31, ty = tid >> 5;
  for (int r = ty; r < 32; r += 8) t[r][tx] = src[(size_t)(k0 + r) * N + n0 + tx];
  __syncthreads();
  for (int r = ty; r < 32; r += 8) dst[(size_t)(n0 + r) * K + k0 + tx] = f2bf(t[tx][r]);
}

__global__ void convqkvT_kernel(const float* __restrict__ wq, const float* __restrict__ wk,
                                const float* __restrict__ wv, u16* __restrict__ dst,
                                long long wz, long long dz) {
  __shared__ float t[32][33];
  int n0 = blockIdx.x * 32, k0 = blockIdx.y * 32;
  int which = n0 / 768;
  int r0 = n0 % 768;
  int h = r0 >> 6, e0 = r0 & 63;
  const float* src = which == 0 ? wq : (which == 1 ? wk : wv);
  src += (size_t)blockIdx.z * wz;
  dst += (size_t)blockIdx.z * dz;
  int tid = threadIdx.x;
  int tx = tid & 31, ty = tid >> 5;
  for (int r = ty; r < 32; r += 8) t[r][tx] = src[(size_t)(h * 768 + k0 + r) * 64 + e0 + tx];
  __syncthreads();
  for (int r = ty; r < 32; r += 8) dst[(size_t)(n0 + r) * 768 + k0 + tx] = f2bf(t[tx][r]);
}

// ---------------------------------------------------------------------------
// v [bh][s][e] -> vt [bh][e][s]
// ---------------------------------------------------------------------------
__global__ void transpose_v_kernel(const u16* __restrict__ v, u16* __restrict__ vt) {
  __shared__ u16 t[64][72];
  int bh = blockIdx.x, sc = blockIdx.y;
  int tid = threadIdx.x;
  const u16* src = v + ((size_t)bh * 1024 + sc * 64) * 64;
  int sl = tid >> 2, e0 = (tid & 3) * 16;
  ushort8v a = *(const ushort8v*)(src + (size_t)sl * 64 + e0);
  ushort8v b = *(const ushort8v*)(src + (size_t)sl * 64 + e0 + 8);
  #pragma unroll
  for (int j = 0; j < 8; ++j) t[sl][e0 + j] = a[j];
  #pragma unroll
  for (int j = 0; j < 8; ++j) t[sl][e0 + 8 + j] = b[j];
  __syncthreads();
  int e = tid >> 2, s0 = (tid & 3) * 16;
  ushort8v o0, o1;
  #pragma unroll
  for (int j = 0; j < 8; ++j) o0[j] = t[s0 + j][e];
  #pragma unroll
  for (int j = 0; j < 8; ++j) o1[j] = t[s0 + 8 + j][e];
  u16* dst = vt + ((size_t)bh * 64 + e) * 1024 + sc * 64 + s0;
  *(ushort8v*)dst = o0;
  *(ushort8v*)(dst + 8) = o1;
}

// ---------------------------------------------------------------------------
// gemm256: C[M,N] = A[M,K]*Wt[N,K], 256x256 tile, 8 waves (wave tile 128x64),
// K as 32-wide slices in a 4-slot LDS ring (128 KB dynamic), counted vmcnt,
// one raw s_barrier per phase, prefetch distance 3 slices. Swizzled slices
// (see stage_slice/ringfrag) -> conflict-free ds_read_b128.
// Race audit: phase ks stages slice ks+3 into slot (ks-1)&3, whose reads
// completed before each wave's lgkmcnt(0) at phase ks-1, which precedes its
// arrival at the phase-ks barrier; the stage is issued after that barrier.
// The wait-then-barrier order makes vmcnt counting cover ALL waves' loads.
// MODE 0: QKV scatter  MODE 1: atomicAdd xf  MODE 2: gelu->bf16  MODE 3: atomicAdd xf (+bias z==0)
// ---------------------------------------------------------------------------
template <int MODE>
__global__ __launch_bounds__(512, 1) void gemm256(
    const u16* __restrict__ A, int lda, const u16* __restrict__ Wt, int ldb, int kChunk,
    float* __restrict__ xf, u16* __restrict__ outb, const float* __restrict__ bias,
    u16* __restrict__ qb, u16* __restrict__ kb, u16* __restrict__ vb) {
  extern __shared__ char lds[];
  int tid = threadIdx.x, lane = tid & 63, w = tid >> 6;
  int wm = w >> 2, wn = w & 3;
  int m0 = blockIdx.x * 256, n0 = blockIdx.y * 256;
  int kb0 = blockIdx.z * kChunk;
  int NK = kChunk >> 5;
  const u16* Ag = A + (size_t)m0 * lda + kb0;
  const u16* Bg = Wt + (size_t)n0 * ldb + kb0;
  f32x4 acc[8][4] = {};
  int lc = lane & 15, t = lane >> 4;

  #pragma unroll
  for (int p = 0; p < 3; ++p) {
    stage_slice(Ag + p * 32, lda, lds + (p & 3) * 32768, tid);
    stage_slice(Bg + p * 32, ldb, lds + (p & 3) * 32768 + 16384, tid);
  }

  for (int ks = 0; ks < NK; ++ks) {
    int newer = NK - 1 - ks;
    if (newer >= 2)      asm volatile("s_waitcnt vmcnt(8)" ::: "memory");
    else if (newer == 1) asm volatile("s_waitcnt vmcnt(4)" ::: "memory");
    else                 asm volatile("s_waitcnt vmcnt(0)" ::: "memory");
    __builtin_amdgcn_sched_barrier(0);
    __builtin_amdgcn_s_barrier();
    __builtin_amdgcn_sched_barrier(0);

    const char* sa = lds + (ks & 3) * 32768;
    const char* sb = sa + 16384;
    bf16x8 af[8], bfr[4];
    #pragma unroll
    for (int mt = 0; mt < 8; ++mt) af[mt] = ringfrag(sa, wm * 128 + mt * 16 + lc, t);
    #pragma unroll
    for (int nt = 0; nt < 4; ++nt) bfr[nt] = ringfrag(sb, wn * 64 + nt * 16 + lc, t);
    if (ks + 3 < NK) {
      stage_slice(Ag + (ks + 3) * 32, lda, lds + ((ks + 3) & 3) * 32768, tid);
      stage_slice(Bg + (ks + 3) * 32, ldb, lds + ((ks + 3) & 3) * 32768 + 16384, tid);
    }
    asm volatile("s_waitcnt lgkmcnt(0)" ::: "memory");
    __builtin_amdgcn_sched_barrier(0);
    __builtin_amdgcn_s_setprio(1);
    #pragma unroll
    for (int mt = 0; mt < 8; ++mt)
      #pragma unroll
      for (int nt = 0; nt < 4; ++nt)
        acc[mt][nt] = MFMA(af[mt], bfr[nt], acc[mt][nt]);
    __builtin_amdgcn_s_setprio(0);
  }

  int rbase = m0 + wm * 128 + (t << 2);
  int cbase = n0 + wn * 64 + lc;
  if constexpr (MODE == 0) {
    int which = n0 / 768;
    u16* dstb = which == 0 ? qb : (which == 1 ? kb : vb);
    int clocal = n0 - which * 768 + wn * 64 + lc;
    #pragma unroll
    for (int mt = 0; mt < 8; ++mt) {
      #pragma unroll
      for (int nt = 0; nt < 4; ++nt) {
        int rr = clocal + nt * 16;
        int h = rr >> 6, e = rr & 63;
        #pragma unroll
        for (int reg = 0; reg < 4; ++reg) {
          int row = rbase + mt * 16 + reg;
          int b = row >> 10, s = row & 1023;
          dstb[((size_t)(b * 12 + h) * 1024 + s) * 64 + e] = f2bf(acc[mt][nt][reg]);
        }
      }
    }
  } else if constexpr (MODE == 2) {
    #pragma unroll
    for (int mt = 0; mt < 8; ++mt) {
      #pragma unroll
      for (int nt = 0; nt < 4; ++nt) {
        int col = cbase + nt * 16;
        float bb = bias[col];
        #pragma unroll
        for (int reg = 0; reg < 4; ++reg) {
          int row = rbase + mt * 16 + reg;
          float tt = acc[mt][nt][reg] + bb;
          float u = tt * fmaf(tt * tt, 0.044715f, 1.0f);
          float ex = __builtin_amdgcn_exp2f(u * -2.3022156f);
          float g = tt * __builtin_amdgcn_rcpf(1.0f + ex);
          outb[(size_t)row * 3072 + col] = f2bf(g);
        }
      }
    }
  } else {
    bool addb = (MODE == 3) && (blockIdx.z == 0);
    #pragma unroll
    for (int mt = 0; mt < 8; ++mt) {
      #pragma unroll
      for (int nt = 0; nt < 4; ++nt) {
        int col = cbase + nt * 16;
        float bb = addb ? bias[col] : 0.0f;
        #pragma unroll
        for (int reg = 0; reg < 4; ++reg) {
          int row = rbase + mt * 16 + reg;
          atomicAdd(&xf[(size_t)row * 768 + col], acc[mt][nt][reg] + bb);
        }
      }
    }
  }
}

// ---------------------------------------------------------------------------
// flash attention, fixed-shift softmax (exact shift-invariance), l = P@ones
// via MFMA. Double-buffered K/V staging: stage kt+1 issued after QK, lands
// during softmax/PV (counted: only slice kt outstanding at the vmcnt(0)).
// q,k: [bh][s][64] ; vt: [bh][e][s] ; o: [b,s, h*64+e]
// ---------------------------------------------------------------------------
__global__ __launch_bounds__(256) void flash64(
    const u16* __restrict__ q, const u16* __restrict__ k, const u16* __restrict__ vt,
    const int* __restrict__ kmask, u16* __restrict__ o) {
  __shared__ alignas(16) u16 Qs[64 * 64];
  __shared__ alignas(16) u16 Ks[2][64 * 64];
  __shared__ alignas(16) u16 Vs[2][64 * 64];
  __shared__ alignas(16) u16 Ps[64 * 64];
  int tid = threadIdx.x, lane = tid & 63, w = tid >> 6;
  int lc = lane & 15;
  int bh = blockIdx.x, q0 = blockIdx.y * 64;
  int b = bh / 12, h = bh % 12;

  stage64(q + ((size_t)bh * 1024 + q0) * 64, 64, Qs, 64, tid);
  __syncthreads();
  int qrow = w * 16 + lc;
  int e0 = (lane >> 4) * 8;
  bf16x8 aq0 = ldsfrag(Qs, qrow, e0);
  bf16x8 aq1 = ldsfrag(Qs, qrow, 32 + e0);

  bf16x8 ones;
  #pragma unroll
  for (int j = 0; j < 8; ++j) ones[j] = (__bf16)1.0f;

  f32x4 oacc[4] = {};
  f32x4 lacc = {};
  const float SCL = 0.125f * 1.44269504f;
  const float SH = -3.0f * 1.44269504f;
  int prow_base = w * 16 + ((lane >> 4) << 2);

  // prologue: stage tile 0
  stage64(k + (size_t)bh * 1024 * 64, 64, Ks[0], 64, tid);
  stage64(vt + (size_t)bh * 64 * 1024, 1024, Vs[0], 64, tid);

  for (int kt = 0; kt < 16; ++kt) {
    asm volatile("s_waitcnt vmcnt(0)" ::: "memory");
    __builtin_amdgcn_sched_barrier(0);
    __builtin_amdgcn_s_barrier();
    __builtin_amdgcn_sched_barrier(0);
    const u16* Kc = Ks[kt & 1];
    const u16* Vc = Vs[kt & 1];

    f32x4 sacc[4] = {};
    #pragma unroll
    for (int nt = 0; nt < 4; ++nt) {
      bf16x8 bk = ldsfrag(Kc, nt * 16 + lc, e0);
      sacc[nt] = MFMA(aq0, bk, sacc[nt]);
    }
    #pragma unroll
    for (int nt = 0; nt < 4; ++nt) {
      bf16x8 bk = ldsfrag(Kc, nt * 16 + lc, 32 + e0);
      sacc[nt] = MFMA(aq1, bk, sacc[nt]);
    }

    // stage next tile into the other slot (lands during softmax/PV below);
    // safe: that slot's reads finished before each wave's MFMA consumption
    // at phase kt-1, which precedes the phase-kt barrier above.
    if (kt + 1 < 16) {
      stage64(k + ((size_t)bh * 1024 + (kt + 1) * 64) * 64, 64, Ks[(kt + 1) & 1], 64, tid);
      stage64(vt + (size_t)bh * 64 * 1024 + (kt + 1) * 64, 1024, Vs[(kt + 1) & 1], 64, tid);
    }

    #pragma unroll
    for (int nt = 0; nt < 4; ++nt) {
      int c = nt * 16 + lc;
      float mk = kmask[b * 1024 + kt * 64 + c] ? SH : -1e30f;
      #pragma unroll
      for (int r = 0; r < 4; ++r) {
        float p = __builtin_amdgcn_exp2f(fmaf(sacc[nt][r], SCL, mk));
        int prow = prow_base + r;
        int boff = prow * 128 + ((c << 1) ^ ((prow & 7) << 4));
        *(u16*)((char*)Ps + boff) = f2bf(p);
      }
    }

    // wave-private P rows; compiler inserts lgkmcnt for write->read dep
    bf16x8 ap0 = ldsfrag(Ps, qrow, e0);
    bf16x8 ap1 = ldsfrag(Ps, qrow, 32 + e0);
    lacc = MFMA(ap0, ones, lacc);
    lacc = MFMA(ap1, ones, lacc);
    #pragma unroll
    for (int et = 0; et < 4; ++et) {
      bf16x8 bv = ldsfrag(Vc, et * 16 + lc, e0);
      oacc[et] = MFMA(ap0, bv, oacc[et]);
    }
    #pragma unroll
    for (int et = 0; et < 4; ++et) {
      bf16x8 bv = ldsfrag(Vc, et * 16 + lc, 32 + e0);
      oacc[et] = MFMA(ap1, bv, oacc[et]);
    }
  }

  float rl[4];
  #pragma unroll
  for (int r = 0; r < 4; ++r) rl[r] = __builtin_amdgcn_rcpf(lacc[r]);
  int orow_base = q0 + prow_base;
  #pragma unroll
  for (int et = 0; et < 4; ++et) {
    int e = et * 16 + lc;
    #pragma unroll
    for (int r = 0; r < 4; ++r) {
      int row = orow_base + r;
      o[((size_t)(b * 1024 + row)) * 768 + h * 64 + e] = f2bf(oacc[et][r] * rl[r]);
    }
  }
}

__global__ void copy_kernel(const float* __restrict__ src, float* __restrict__ dst) {
  size_t i = (size_t)blockIdx.x * blockDim.x + threadIdx.x;
  ((float4v*)dst)[i] = ((const float4v*)src)[i];
}

// ---------------------------------------------------------------------------
extern "C" void kernel_launch(void* const* d_in, const int* in_sizes, int n_in,
                              void* d_out, int out_size, void* d_ws, size_t ws_size,
                              hipStream_t stream) {
  const int* tokens = (const int*)d_in[0];
  const int* kmask = (const int*)d_in[1];
  const float* emb = (const float*)d_in[2];
  const float* pe = (const float*)d_in[3];
  const float* ln1_s = (const float*)d_in[4];
  const float* ln1_b = (const float*)d_in[5];
  const float* wq = (const float*)d_in[6];
  const float* wk = (const float*)d_in[7];
  const float* wv = (const float*)d_in[8];
  const float* wo = (const float*)d_in[9];
  const float* ln2_s = (const float*)d_in[10];
  const float* ln2_b = (const float*)d_in[11];
  const float* w1 = (const float*)d_in[12];
  const float* b1 = (const float*)d_in[13];
  const float* w2 = (const float*)d_in[14];
  const float* b2 = (const float*)d_in[15];

  (void)hipFuncSetAttribute((const void*)gemm256<0>, hipFuncAttributeMaxDynamicSharedMemorySize, 131072);
  (void)hipFuncSetAttribute((const void*)gemm256<1>, hipFuncAttributeMaxDynamicSharedMemorySize, 131072);
  (void)hipFuncSetAttribute((const void*)gemm256<2>, hipFuncAttributeMaxDynamicSharedMemorySize, 131072);
  (void)hipFuncSetAttribute((const void*)gemm256<3>, hipFuncAttributeMaxDynamicSharedMemorySize, 131072);

  char* ws = (char*)d_ws;
  float* xf = (float*)ws;                       // 8192*768*4
  u16* xn   = (u16*)(ws + 25165824);
  u16* qb   = (u16*)(ws + 37748736);
  u16* kb   = (u16*)(ws + 50331648);
  u16* vb   = (u16*)(ws + 62914560);
  u16* vtb  = (u16*)(ws + 75497472);
  u16* ob   = (u16*)(ws + 88080384);
  u16* ffh  = (u16*)(ws + 100663296);           // 8192*3072*2

  const size_t SZ_QKV = (size_t)2304 * 768;
  const size_t SZ_O   = (size_t)768 * 768;
  const size_t SZ_F1  = (size_t)3072 * 768;
  const size_t SZ_F2  = (size_t)768 * 3072;
  const size_t NEED = 150994944 + 2 * 6 * (SZ_QKV + SZ_O + SZ_F1 + SZ_F2);
  bool pre = ws_size >= NEED;
  int nz = pre ? 6 : 1;
  u16* wqkvt = (u16*)(ws + 150994944);
  u16* wot   = wqkvt + (size_t)nz * SZ_QKV;
  u16* w1t   = wot + (size_t)nz * SZ_O;
  u16* w2t   = w1t + (size_t)nz * SZ_F1;

  embed_kernel<<<8192, 192, 0, stream>>>(tokens, emb, pe, xf);

  if (pre) {
    convqkvT_kernel<<<dim3(72, 24, 6), 256, 0, stream>>>(wq, wk, wv, wqkvt, 589824LL, (long long)SZ_QKV);
    convT_kernel<<<dim3(24, 24, 6), 256, 0, stream>>>(wo, wot, 768, 768, 589824LL, (long long)SZ_O);
    convT_kernel<<<dim3(96, 24, 6), 256, 0, stream>>>(w1, w1t, 3072, 768, 2359296LL, (long long)SZ_F1);
    convT_kernel<<<dim3(24, 96, 6), 256, 0, stream>>>(w2, w2t, 768, 3072, 2359296LL, (long long)SZ_F2);
  }

  for (int l = 0; l < 6; ++l) {
    size_t woff_qkv = (size_t)l * 12 * 768 * 64;
    size_t woff_o = (size_t)l * 768 * 768;
    size_t woff_ff = (size_t)l * 768 * 3072;
    const u16* wt_qkv_l = wqkvt + (pre ? (size_t)l * SZ_QKV : 0);
    const u16* wt_o_l   = wot   + (pre ? (size_t)l * SZ_O   : 0);
    const u16* wt_1_l   = w1t   + (pre ? (size_t)l * SZ_F1  : 0);
    const u16* wt_2_l   = w2t   + (pre ? (size_t)l * SZ_F2  : 0);

    if (!pre) {
      convqkvT_kernel<<<dim3(72, 24, 1), 256, 0, stream>>>(wq + woff_qkv, wk + woff_qkv, wv + woff_qkv, (u16*)wt_qkv_l, 0LL, 0LL);
      convT_kernel<<<dim3(24, 24, 1), 256, 0, stream>>>(wo + woff_o, (u16*)wt_o_l, 768, 768, 0LL, 0LL);
      convT_kernel<<<dim3(96, 24, 1), 256, 0, stream>>>(w1 + woff_ff, (u16*)wt_1_l, 3072, 768, 0LL, 0LL);
      convT_kernel<<<dim3(24, 96, 1), 256, 0, stream>>>(w2 + woff_ff, (u16*)wt_2_l, 768, 3072, 0LL, 0LL);
    }

    ln_kernel<<<8192, 192, 0, stream>>>(xf, ln1_s + l * 768, ln1_b + l * 768, xn);
    gemm256<0><<<dim3(32, 9, 1), 512, 131072, stream>>>(xn, 768, wt_qkv_l, 768, 768, nullptr, nullptr, nullptr, qb, kb, vb);
    transpose_v_kernel<<<dim3(96, 16), 256, 0, stream>>>(vb, vtb);
    flash64<<<dim3(96, 16), 256, 0, stream>>>(qb, kb, vtb, kmask, ob);
    gemm256<1><<<dim3(32, 3, 3), 512, 131072, stream>>>(ob, 768, wt_o_l, 768, 256, xf, nullptr, nullptr, nullptr, nullptr, nullptr);
    ln_kernel<<<8192, 192, 0, stream>>>(xf, ln2_s + l * 768, ln2_b + l * 768, xn);
    gemm256<2><<<dim3(32, 12, 1), 512, 131072, stream>>>(xn, 768, wt_1_l, 768, 768, nullptr, ffh, b1 + l * 3072, nullptr, nullptr, nullptr);
    gemm256<3><<<dim3(32, 3, 3), 512, 131072, stream>>>(ffh, 3072, wt_2_l, 3072, 1024, xf, nullptr, b2 + l * 768, nullptr, nullptr, nullptr);
  }

  copy_kernel<<<6144, 256, 0, stream>>>(xf, (float*)d_out);
}

// Round 5
// 1830.123 us; speedup vs baseline: 1.2504x; 1.2339x over previous
//
#include <hip/hip_runtime.h>
#include <math.h>

typedef unsigned short u16;
typedef unsigned int u32;
typedef __attribute__((ext_vector_type(8))) __bf16 bf16x8;
typedef __attribute__((ext_vector_type(4))) float f32x4;
typedef __attribute__((ext_vector_type(8))) unsigned short ushort8v;
typedef __attribute__((ext_vector_type(4))) float float4v;
typedef __attribute__((ext_vector_type(4))) unsigned short u16x4;

typedef const __attribute__((address_space(1))) void gvoid_t;
typedef __attribute__((address_space(3))) void lvoid_t;

#define MFMA(a, b, c) __builtin_amdgcn_mfma_f32_16x16x32_bf16((a), (b), (c), 0, 0, 0)

// native RNE f32->bf16
__device__ __forceinline__ u16 f2bf(float f) {
  __bf16 h = (__bf16)f;
  return __builtin_bit_cast(u16, h);
}

// ---------------------------------------------------------------------------
// [rows][64] bf16 tiles (128B rows), XOR-swizzled source + swizzled reads
// (involution (r&7)<<4) -> conflict-free ds_read_b128. (proven 0-conflict)
// ---------------------------------------------------------------------------
__device__ __forceinline__ void stage64(const u16* g, int ldg, u16* lds, int rows, int tid) {
  int w = tid >> 6, l = tid & 63;
  int lr = l >> 3;
  int cb = (l & 7) << 4;
  for (int it = 0; it < rows; it += 32) {
    int rbase = it + w * 8;
    int r = rbase + lr;
    int scb = cb ^ ((r & 7) << 4);
    const char* gp = (const char*)(g + (size_t)r * ldg) + scb;
    char* lp = (char*)lds + (size_t)rbase * 128;
    __builtin_amdgcn_global_load_lds((gvoid_t*)gp, (lvoid_t*)lp, 16, 0, 0);
  }
}

__device__ __forceinline__ bf16x8 ldsfrag(const u16* base, int row, int e0) {
  int boff = row * 128 + (((e0) << 1) ^ ((row & 7) << 4));
  return *(const bf16x8*)((const char*)base + boff);
}

// ---------------------------------------------------------------------------
// embed
// ---------------------------------------------------------------------------
__global__ void embed_kernel(const int* __restrict__ tok, const float* __restrict__ emb,
                             const float* __restrict__ pe, float* __restrict__ xf) {
  int row = blockIdx.x;
  int tid = threadIdx.x;              // 192
  int t = tok[row];
  int spos = row & 1023;
  float4v e = ((const float4v*)(emb + (size_t)t * 768))[tid];
  float4v p = ((const float4v*)(pe + (size_t)spos * 768))[tid];
  float4v r;
  r.x = e.x + p.x; r.y = e.y + p.y; r.z = e.z + p.z; r.w = e.w + p.w;
  ((float4v*)(xf + (size_t)row * 768))[tid] = r;
}

// ---------------------------------------------------------------------------
// layernorm
// ---------------------------------------------------------------------------
__global__ void ln_kernel(const float* __restrict__ x, const float* __restrict__ sc,
                          const float* __restrict__ bi, u16* __restrict__ out) {
  int row = blockIdx.x;
  int tid = threadIdx.x;  // 192
  float4v v = ((const float4v*)(x + (size_t)row * 768))[tid];
  float s = v.x + v.y + v.z + v.w;
  float s2 = v.x * v.x + v.y * v.y + v.z * v.z + v.w * v.w;
  #pragma unroll
  for (int off = 32; off >= 1; off >>= 1) {
    s += __shfl_down(s, off);
    s2 += __shfl_down(s2, off);
  }
  __shared__ float red[8];
  if ((tid & 63) == 0) { red[tid >> 6] = s; red[4 + (tid >> 6)] = s2; }
  __syncthreads();
  float S = red[0] + red[1] + red[2];
  float S2 = red[4] + red[5] + red[6];
  float m = S * (1.0f / 768.0f);
  float var = S2 * (1.0f / 768.0f) - m * m;
  float rs = rsqrtf(var + 1e-5f);
  float4v sv = ((const float4v*)sc)[tid];
  float4v bv = ((const float4v*)bi)[tid];
  u16x4 ov;
  ov.x = f2bf((v.x - m) * rs * sv.x + bv.x);
  ov.y = f2bf((v.y - m) * rs * sv.y + bv.y);
  ov.z = f2bf((v.z - m) * rs * sv.z + bv.z);
  ov.w = f2bf((v.w - m) * rs * sv.w + bv.w);
  *(u16x4*)(out + (size_t)row * 768 + tid * 4) = ov;
}

// ---------------------------------------------------------------------------
// weight converters: f32 [K][N] -> bf16 [N][K]
// ---------------------------------------------------------------------------
__global__ void convT_kernel(const float* __restrict__ src, u16* __restrict__ dst,
                             int N, int K, long long sz, long long dz) {
  src += (size_t)blockIdx.z * sz;
  dst += (size_t)blockIdx.z * dz;
  __shared__ float t[32][33];
  int n0 = blockIdx.x * 32, k0 = blockIdx.y * 32;
  int tid = threadIdx.x;
  int tx = tid & 31, ty = tid >> 5;
  for (int r = ty; r < 32; r += 8) t[r][tx] = src[(size_t)(k0 + r) * N + n0 + tx];
  __syncthreads();
  for (int r = ty; r < 32; r += 8) dst[(size_t)(n0 + r) * K + k0 + tx] = f2bf(t[tx][r]);
}

__global__ void convqkvT_kernel(const float* __restrict__ wq, const float* __restrict__ wk,
                                const float* __restrict__ wv, u16* __restrict__ dst,
                                long long wz, long long dz) {
  __shared__ float t[32][33];
  int n0 = blockIdx.x * 32, k0 = blockIdx.y * 32;
  int which = n0 / 768;
  int r0 = n0 % 768;
  int h = r0 >> 6, e0 = r0 & 63;
  const float* src = which == 0 ? wq : (which == 1 ? wk : wv);
  src += (size_t)blockIdx.z * wz;
  dst += (size_t)blockIdx.z * dz;
  int tid = threadIdx.x;
  int tx = tid & 31, ty = tid >> 5;
  for (int r = ty; r < 32; r += 8) t[r][tx] = src[(size_t)(h * 768 + k0 + r) * 64 + e0 + tx];
  __syncthreads();
  for (int r = ty; r < 32; r += 8) dst[(size_t)(n0 + r) * 768 + k0 + tx] = f2bf(t[tx][r]);
}

// ---------------------------------------------------------------------------
// v [bh][s][e] -> vt [bh][e][s]
// ---------------------------------------------------------------------------
__global__ void transpose_v_kernel(const u16* __restrict__ v, u16* __restrict__ vt) {
  __shared__ u16 t[64][72];
  int bh = blockIdx.x, sc = blockIdx.y;
  int tid = threadIdx.x;
  const u16* src = v + ((size_t)bh * 1024 + sc * 64) * 64;
  int sl = tid >> 2, e0 = (tid & 3) * 16;
  ushort8v a = *(const ushort8v*)(src + (size_t)sl * 64 + e0);
  ushort8v b = *(const ushort8v*)(src + (size_t)sl * 64 + e0 + 8);
  #pragma unroll
  for (int j = 0; j < 8; ++j) t[sl][e0 + j] = a[j];
  #pragma unroll
  for (int j = 0; j < 8; ++j) t[sl][e0 + 8 + j] = b[j];
  __syncthreads();
  int e = tid >> 2, s0 = (tid & 3) * 16;
  ushort8v o0, o1;
  #pragma unroll
  for (int j = 0; j < 8; ++j) o0[j] = t[s0 + j][e];
  #pragma unroll
  for (int j = 0; j < 8; ++j) o1[j] = t[s0 + 8 + j][e];
  u16* dst = vt + ((size_t)bh * 64 + e) * 1024 + sc * 64 + s0;
  *(ushort8v*)dst = o0;
  *(ushort8v*)(dst + 8) = o1;
}

// ---------------------------------------------------------------------------
// gemm128 (proven round-2 structure): C[M,N] = A[M,K]*Wt[N,K], 128x128 tile,
// BK=64, 4 waves (wave tile 64x64), __syncthreads 2-barrier loop,
// global_load_lds width-16 staging, both-sides XOR swizzle. NK = K-steps
// (compile-time -> full unroll + hoisted addressing). blockIdx.z = K-split
// chunk; MODE 1/3 accumulate via atomicAdd (deterministic-enough, threshold-
// checked; proven rounds 3-4).
// MODE 0: QKV scatter  MODE 1: atomicAdd xf  MODE 2: gelu->bf16  MODE 3: atomicAdd xf (+bias z==0)
// ---------------------------------------------------------------------------
template <int MODE, int NK>
__global__ __launch_bounds__(256) void gemm128(
    const u16* __restrict__ A, int lda, const u16* __restrict__ Wt, int ldb,
    float* __restrict__ xf, u16* __restrict__ outb, const float* __restrict__ bias,
    u16* __restrict__ qb, u16* __restrict__ kb, u16* __restrict__ vb) {
  __shared__ alignas(16) u16 As[128 * 64];
  __shared__ alignas(16) u16 Bs[128 * 64];
  int tid = threadIdx.x, lane = tid & 63, w = tid >> 6;
  int wm = w >> 1, wn = w & 1;
  int m0 = blockIdx.x * 128, n0 = blockIdx.y * 128;
  int kb0 = blockIdx.z * (NK * 64);
  f32x4 acc[4][4] = {};
  // staging addresses, hoisted: row r = i*32 + w*8 + lr, source 16B-slot cb^(lr<<4)
  int lr = lane >> 3;
  int cb = (lane & 7) << 4;
  int sws = cb ^ (lr << 4);
  const char* pA = (const char*)(A + (size_t)m0 * lda + kb0) + (size_t)(w * 8 + lr) * (lda * 2) + sws;
  const char* pB = (const char*)(Wt + (size_t)n0 * ldb + kb0) + (size_t)(w * 8 + lr) * (ldb * 2) + sws;
  char* dA = (char*)As + w * 1024;   // wave-uniform dest (+lane*16 implicit)
  char* dB = (char*)Bs + w * 1024;
  int arow = wm * 64 + (lane & 15);
  int brow = wn * 64 + (lane & 15);
  int e0 = (lane >> 4) * 8;
  #pragma unroll
  for (int kt = 0; kt < NK; ++kt) {
    __syncthreads();
    #pragma unroll
    for (int i = 0; i < 4; ++i) {
      __builtin_amdgcn_global_load_lds((gvoid_t*)(pA + (size_t)i * 32 * (lda * 2)),
                                       (lvoid_t*)(dA + i * 4096), 16, 0, 0);
      __builtin_amdgcn_global_load_lds((gvoid_t*)(pB + (size_t)i * 32 * (ldb * 2)),
                                       (lvoid_t*)(dB + i * 4096), 16, 0, 0);
    }
    pA += 128; pB += 128;
    __syncthreads();   // compiler emits vmcnt(0) drain here (staged data ready)
    #pragma unroll
    for (int kk = 0; kk < 2; ++kk) {
      bf16x8 af[4], bfr[4];
      #pragma unroll
      for (int mt = 0; mt < 4; ++mt) af[mt] = ldsfrag(As, arow + mt * 16, kk * 32 + e0);
      #pragma unroll
      for (int nt = 0; nt < 4; ++nt) bfr[nt] = ldsfrag(Bs, brow + nt * 16, kk * 32 + e0);
      #pragma unroll
      for (int mt = 0; mt < 4; ++mt)
        #pragma unroll
        for (int nt = 0; nt < 4; ++nt)
          acc[mt][nt] = MFMA(af[mt], bfr[nt], acc[mt][nt]);
    }
  }
  int rbase = m0 + wm * 64 + ((lane >> 4) << 2);
  int cbase = n0 + wn * 64 + (lane & 15);
  if constexpr (MODE == 0) {
    int which = n0 / 768;
    u16* dstb = which == 0 ? qb : (which == 1 ? kb : vb);
    int cloc = cbase - which * 768;
    #pragma unroll
    for (int mt = 0; mt < 4; ++mt) {
      #pragma unroll
      for (int nt = 0; nt < 4; ++nt) {
        int rr = cloc + nt * 16;
        int h = rr >> 6, e = rr & 63;
        #pragma unroll
        for (int reg = 0; reg < 4; ++reg) {
          int row = rbase + mt * 16 + reg;
          int b = row >> 10, s = row & 1023;
          dstb[((size_t)(b * 12 + h) * 1024 + s) * 64 + e] = f2bf(acc[mt][nt][reg]);
        }
      }
    }
  } else if constexpr (MODE == 2) {
    #pragma unroll
    for (int mt = 0; mt < 4; ++mt) {
      #pragma unroll
      for (int nt = 0; nt < 4; ++nt) {
        int col = cbase + nt * 16;
        float bb = bias[col];
        #pragma unroll
        for (int reg = 0; reg < 4; ++reg) {
          int row = rbase + mt * 16 + reg;
          float t = acc[mt][nt][reg] + bb;
          float u = t * fmaf(t * t, 0.044715f, 1.0f);
          float ex = __builtin_amdgcn_exp2f(u * -2.3022156f);
          float g = t * __builtin_amdgcn_rcpf(1.0f + ex);
          outb[(size_t)row * 3072 + col] = f2bf(g);
        }
      }
    }
  } else {
    bool addb = (MODE == 3) && (blockIdx.z == 0);
    #pragma unroll
    for (int mt = 0; mt < 4; ++mt) {
      #pragma unroll
      for (int nt = 0; nt < 4; ++nt) {
        int col = cbase + nt * 16;
        float bb = addb ? bias[col] : 0.0f;
        #pragma unroll
        for (int reg = 0; reg < 4; ++reg) {
          int row = rbase + mt * 16 + reg;
          atomicAdd(&xf[(size_t)row * 768 + col], acc[mt][nt][reg] + bb);
        }
      }
    }
  }
}

// ---------------------------------------------------------------------------
// flash attention, fixed-shift softmax (exact shift-invariance), l = P@ones
// via MFMA, double-buffered K/V staging (stage kt+1 lands during softmax/PV).
// q,k: [bh][s][64] ; vt: [bh][e][s] ; o: [b,s, h*64+e]
// ---------------------------------------------------------------------------
__global__ __launch_bounds__(256) void flash64(
    const u16* __restrict__ q, const u16* __restrict__ k, const u16* __restrict__ vt,
    const int* __restrict__ kmask, u16* __restrict__ o) {
  __shared__ alignas(16) u16 Qs[64 * 64];
  __shared__ alignas(16) u16 Ks[2][64 * 64];
  __shared__ alignas(16) u16 Vs[2][64 * 64];
  __shared__ alignas(16) u16 Ps[64 * 64];
  int tid = threadIdx.x, lane = tid & 63, w = tid >> 6;
  int lc = lane & 15;
  int bh = blockIdx.x, q0 = blockIdx.y * 64;
  int b = bh / 12, h = bh % 12;

  stage64(q + ((size_t)bh * 1024 + q0) * 64, 64, Qs, 64, tid);
  __syncthreads();
  int qrow = w * 16 + lc;
  int e0 = (lane >> 4) * 8;
  bf16x8 aq0 = ldsfrag(Qs, qrow, e0);
  bf16x8 aq1 = ldsfrag(Qs, qrow, 32 + e0);

  bf16x8 ones;
  #pragma unroll
  for (int j = 0; j < 8; ++j) ones[j] = (__bf16)1.0f;

  f32x4 oacc[4] = {};
  f32x4 lacc = {};
  const float SCL = 0.125f * 1.44269504f;
  const float SH = -3.0f * 1.44269504f;
  int prow_base = w * 16 + ((lane >> 4) << 2);

  stage64(k + (size_t)bh * 1024 * 64, 64, Ks[0], 64, tid);
  stage64(vt + (size_t)bh * 64 * 1024, 1024, Vs[0], 64, tid);

  for (int kt = 0; kt < 16; ++kt) {
    asm volatile("s_waitcnt vmcnt(0)" ::: "memory");
    __builtin_amdgcn_sched_barrier(0);
    __builtin_amdgcn_s_barrier();
    __builtin_amdgcn_sched_barrier(0);
    const u16* Kc = Ks[kt & 1];
    const u16* Vc = Vs[kt & 1];

    f32x4 sacc[4] = {};
    #pragma unroll
    for (int nt = 0; nt < 4; ++nt) {
      bf16x8 bk = ldsfrag(Kc, nt * 16 + lc, e0);
      sacc[nt] = MFMA(aq0, bk, sacc[nt]);
    }
    #pragma unroll
    for (int nt = 0; nt < 4; ++nt) {
      bf16x8 bk = ldsfrag(Kc, nt * 16 + lc, 32 + e0);
      sacc[nt] = MFMA(aq1, bk, sacc[nt]);
    }

    if (kt + 1 < 16) {
      stage64(k + ((size_t)bh * 1024 + (kt + 1) * 64) * 64, 64, Ks[(kt + 1) & 1], 64, tid);
      stage64(vt + (size_t)bh * 64 * 1024 + (kt + 1) * 64, 1024, Vs[(kt + 1) & 1], 64, tid);
    }

    #pragma unroll
    for (int nt = 0; nt < 4; ++nt) {
      int c = nt * 16 + lc;
      float mk = kmask[b * 1024 + kt * 64 + c] ? SH : -1e30f;
      #pragma unroll
      for (int r = 0; r < 4; ++r) {
        float p = __builtin_amdgcn_exp2f(fmaf(sacc[nt][r], SCL, mk));
        int prow = prow_base + r;
        int boff = prow * 128 + ((c << 1) ^ ((prow & 7) << 4));
        *(u16*)((char*)Ps + boff) = f2bf(p);
      }
    }

    bf16x8 ap0 = ldsfrag(Ps, qrow, e0);
    bf16x8 ap1 = ldsfrag(Ps, qrow, 32 + e0);
    lacc = MFMA(ap0, ones, lacc);
    lacc = MFMA(ap1, ones, lacc);
    #pragma unroll
    for (int et = 0; et < 4; ++et) {
      bf16x8 bv = ldsfrag(Vc, et * 16 + lc, e0);
      oacc[et] = MFMA(ap0, bv, oacc[et]);
    }
    #pragma unroll
    for (int et = 0; et < 4; ++et) {
      bf16x8 bv = ldsfrag(Vc, et * 16 + lc, 32 + e0);
      oacc[et] = MFMA(ap1, bv, oacc[et]);
    }
  }

  float rl[4];
  #pragma unroll
  for (int r = 0; r < 4; ++r) rl[r] = __builtin_amdgcn_rcpf(lacc[r]);
  int orow_base = q0 + prow_base;
  #pragma unroll
  for (int et = 0; et < 4; ++et) {
    int e = et * 16 + lc;
    #pragma unroll
    for (int r = 0; r < 4; ++r) {
      int row = orow_base + r;
      o[((size_t)(b * 1024 + row)) * 768 + h * 64 + e] = f2bf(oacc[et][r] * rl[r]);
    }
  }
}

__global__ void copy_kernel(const float* __restrict__ src, float* __restrict__ dst) {
  size_t i = (size_t)blockIdx.x * blockDim.x + threadIdx.x;
  ((float4v*)dst)[i] = ((const float4v*)src)[i];
}

// ---------------------------------------------------------------------------
extern "C" void kernel_launch(void* const* d_in, const int* in_sizes, int n_in,
                              void* d_out, int out_size, void* d_ws, size_t ws_size,
                              hipStream_t stream) {
  const int* tokens = (const int*)d_in[0];
  const int* kmask = (const int*)d_in[1];
  const float* emb = (const float*)d_in[2];
  const float* pe = (const float*)d_in[3];
  const float* ln1_s = (const float*)d_in[4];
  const float* ln1_b = (const float*)d_in[5];
  const float* wq = (const float*)d_in[6];
  const float* wk = (const float*)d_in[7];
  const float* wv = (const float*)d_in[8];
  const float* wo = (const float*)d_in[9];
  const float* ln2_s = (const float*)d_in[10];
  const float* ln2_b = (const float*)d_in[11];
  const float* w1 = (const float*)d_in[12];
  const float* b1 = (const float*)d_in[13];
  const float* w2 = (const float*)d_in[14];
  const float* b2 = (const float*)d_in[15];

  char* ws = (char*)d_ws;
  float* xf = (float*)ws;                       // 8192*768*4
  u16* xn   = (u16*)(ws + 25165824);
  u16* qb   = (u16*)(ws + 37748736);
  u16* kb   = (u16*)(ws + 50331648);
  u16* vb   = (u16*)(ws + 62914560);
  u16* vtb  = (u16*)(ws + 75497472);
  u16* ob   = (u16*)(ws + 88080384);
  u16* ffh  = (u16*)(ws + 100663296);           // 8192*3072*2

  const size_t SZ_QKV = (size_t)2304 * 768;
  const size_t SZ_O   = (size_t)768 * 768;
  const size_t SZ_F1  = (size_t)3072 * 768;
  const size_t SZ_F2  = (size_t)768 * 3072;
  const size_t NEED = 150994944 + 2 * 6 * (SZ_QKV + SZ_O + SZ_F1 + SZ_F2);
  bool pre = ws_size >= NEED;
  int nz = pre ? 6 : 1;
  u16* wqkvt = (u16*)(ws + 150994944);
  u16* wot   = wqkvt + (size_t)nz * SZ_QKV;
  u16* w1t   = wot + (size_t)nz * SZ_O;
  u16* w2t   = w1t + (size_t)nz * SZ_F1;

  embed_kernel<<<8192, 192, 0, stream>>>(tokens, emb, pe, xf);

  if (pre) {
    convqkvT_kernel<<<dim3(72, 24, 6), 256, 0, stream>>>(wq, wk, wv, wqkvt, 589824LL, (long long)SZ_QKV);
    convT_kernel<<<dim3(24, 24, 6), 256, 0, stream>>>(wo, wot, 768, 768, 589824LL, (long long)SZ_O);
    convT_kernel<<<dim3(96, 24, 6), 256, 0, stream>>>(w1, w1t, 3072, 768, 2359296LL, (long long)SZ_F1);
    convT_kernel<<<dim3(24, 96, 6), 256, 0, stream>>>(w2, w2t, 768, 3072, 2359296LL, (long long)SZ_F2);
  }

  for (int l = 0; l < 6; ++l) {
    size_t woff_qkv = (size_t)l * 12 * 768 * 64;
    size_t woff_o = (size_t)l * 768 * 768;
    size_t woff_ff = (size_t)l * 768 * 3072;
    const u16* wt_qkv_l = wqkvt + (pre ? (size_t)l * SZ_QKV : 0);
    const u16* wt_o_l   = wot   + (pre ? (size_t)l * SZ_O   : 0);
    const u16* wt_1_l   = w1t   + (pre ? (size_t)l * SZ_F1  : 0);
    const u16* wt_2_l   = w2t   + (pre ? (size_t)l * SZ_F2  : 0);

    if (!pre) {
      convqkvT_kernel<<<dim3(72, 24, 1), 256, 0, stream>>>(wq + woff_qkv, wk + woff_qkv, wv + woff_qkv, (u16*)wt_qkv_l, 0LL, 0LL);
      convT_kernel<<<dim3(24, 24, 1), 256, 0, stream>>>(wo + woff_o, (u16*)wt_o_l, 768, 768, 0LL, 0LL);
      convT_kernel<<<dim3(96, 24, 1), 256, 0, stream>>>(w1 + woff_ff, (u16*)wt_1_l, 3072, 768, 0LL, 0LL);
      convT_kernel<<<dim3(24, 96, 1), 256, 0, stream>>>(w2 + woff_ff, (u16*)wt_2_l, 768, 3072, 0LL, 0LL);
    }

    ln_kernel<<<8192, 192, 0, stream>>>(xf, ln1_s + l * 768, ln1_b + l * 768, xn);
    gemm128<0, 12><<<dim3(64, 18, 1), 256, 0, stream>>>(xn, 768, wt_qkv_l, 768, nullptr, nullptr, nullptr, qb, kb, vb);
    transpose_v_kernel<<<dim3(96, 16), 256, 0, stream>>>(vb, vtb);
    flash64<<<dim3(96, 16), 256, 0, stream>>>(qb, kb, vtb, kmask, ob);
    gemm128<1, 6><<<dim3(64, 6, 2), 256, 0, stream>>>(ob, 768, wt_o_l, 768, xf, nullptr, nullptr, nullptr, nullptr, nullptr);
    ln_kernel<<<8192, 192, 0, stream>>>(xf, ln2_s + l * 768, ln2_b + l * 768, xn);
    gemm128<2, 12><<<dim3(64, 24, 1), 256, 0, stream>>>(xn, 768, wt_1_l, 768, nullptr, ffh, b1 + l * 3072, nullptr, nullptr, nullptr);
    gemm128<3, 16><<<dim3(64, 6, 3), 256, 0, stream>>>(ffh, 3072, wt_2_l, 3072, xf, nullptr, b2 + l * 768, nullptr, nullptr, nullptr);
  }

  copy_kernel<<<6144, 256, 0, stream>>>(xf, (float*)d_out);
}

// Round 6
// 1594.325 us; speedup vs baseline: 1.4353x; 1.1479x over previous
//
#include <hip/hip_runtime.h>
#include <math.h>

typedef unsigned short u16;
typedef unsigned int u32;
typedef __attribute__((ext_vector_type(8))) __bf16 bf16x8;
typedef __attribute__((ext_vector_type(4))) float f32x4;
typedef __attribute__((ext_vector_type(8))) unsigned short ushort8v;
typedef __attribute__((ext_vector_type(4))) float float4v;
typedef __attribute__((ext_vector_type(4))) unsigned short u16x4;

typedef const __attribute__((address_space(1))) void gvoid_t;
typedef __attribute__((address_space(3))) void lvoid_t;

#define MFMA(a, b, c) __builtin_amdgcn_mfma_f32_16x16x32_bf16((a), (b), (c), 0, 0, 0)

// native RNE f32->bf16
__device__ __forceinline__ u16 f2bf(float f) {
  __bf16 h = (__bf16)f;
  return __builtin_bit_cast(u16, h);
}

// ---------------------------------------------------------------------------
// [rows][64] bf16 tiles (128B rows), XOR-swizzled source + swizzled reads
// (involution (r&7)<<4) -> conflict-free ds_read_b128. (proven 0-conflict)
// ---------------------------------------------------------------------------
__device__ __forceinline__ void stage64(const u16* g, int ldg, u16* lds, int rows, int tid) {
  int w = tid >> 6, l = tid & 63;
  int lr = l >> 3;
  int cb = (l & 7) << 4;
  for (int it = 0; it < rows; it += 32) {
    int rbase = it + w * 8;
    int r = rbase + lr;
    int scb = cb ^ ((r & 7) << 4);
    const char* gp = (const char*)(g + (size_t)r * ldg) + scb;
    char* lp = (char*)lds + (size_t)rbase * 128;
    __builtin_amdgcn_global_load_lds((gvoid_t*)gp, (lvoid_t*)lp, 16, 0, 0);
  }
}

__device__ __forceinline__ bf16x8 ldsfrag(const u16* base, int row, int e0) {
  int boff = row * 128 + (((e0) << 1) ^ ((row & 7) << 4));
  return *(const bf16x8*)((const char*)base + boff);
}

// ---------------------------------------------------------------------------
// embed
// ---------------------------------------------------------------------------
__global__ void embed_kernel(const int* __restrict__ tok, const float* __restrict__ emb,
                             const float* __restrict__ pe, float* __restrict__ xf) {
  int row = blockIdx.x;
  int tid = threadIdx.x;              // 192
  int t = tok[row];
  int spos = row & 1023;
  float4v e = ((const float4v*)(emb + (size_t)t * 768))[tid];
  float4v p = ((const float4v*)(pe + (size_t)spos * 768))[tid];
  float4v r;
  r.x = e.x + p.x; r.y = e.y + p.y; r.z = e.z + p.z; r.w = e.w + p.w;
  ((float4v*)(xf + (size_t)row * 768))[tid] = r;
}

// ---------------------------------------------------------------------------
// layernorm
// ---------------------------------------------------------------------------
__global__ void ln_kernel(const float* __restrict__ x, const float* __restrict__ sc,
                          const float* __restrict__ bi, u16* __restrict__ out) {
  int row = blockIdx.x;
  int tid = threadIdx.x;  // 192
  float4v v = ((const float4v*)(x + (size_t)row * 768))[tid];
  float s = v.x + v.y + v.z + v.w;
  float s2 = v.x * v.x + v.y * v.y + v.z * v.z + v.w * v.w;
  #pragma unroll
  for (int off = 32; off >= 1; off >>= 1) {
    s += __shfl_down(s, off);
    s2 += __shfl_down(s2, off);
  }
  __shared__ float red[8];
  if ((tid & 63) == 0) { red[tid >> 6] = s; red[4 + (tid >> 6)] = s2; }
  __syncthreads();
  float S = red[0] + red[1] + red[2];
  float S2 = red[4] + red[5] + red[6];
  float m = S * (1.0f / 768.0f);
  float var = S2 * (1.0f / 768.0f) - m * m;
  float rs = rsqrtf(var + 1e-5f);
  float4v sv = ((const float4v*)sc)[tid];
  float4v bv = ((const float4v*)bi)[tid];
  u16x4 ov;
  ov.x = f2bf((v.x - m) * rs * sv.x + bv.x);
  ov.y = f2bf((v.y - m) * rs * sv.y + bv.y);
  ov.z = f2bf((v.z - m) * rs * sv.z + bv.z);
  ov.w = f2bf((v.w - m) * rs * sv.w + bv.w);
  *(u16x4*)(out + (size_t)row * 768 + tid * 4) = ov;
}

// ---------------------------------------------------------------------------
// weight converters: f32 [K][N] -> bf16 [N][K]
// ---------------------------------------------------------------------------
__global__ void convT_kernel(const float* __restrict__ src, u16* __restrict__ dst,
                             int N, int K, long long sz, long long dz) {
  src += (size_t)blockIdx.z * sz;
  dst += (size_t)blockIdx.z * dz;
  __shared__ float t[32][33];
  int n0 = blockIdx.x * 32, k0 = blockIdx.y * 32;
  int tid = threadIdx.x;
  int tx = tid & 31, ty = tid >> 5;
  for (int r = ty; r < 32; r += 8) t[r][tx] = src[(size_t)(k0 + r) * N + n0 + tx];
  __syncthreads();
  for (int r = ty; r < 32; r += 8) dst[(size_t)(n0 + r) * K + k0 + tx] = f2bf(t[tx][r]);
}

__global__ void convqkvT_kernel(const float* __restrict__ wq, const float* __restrict__ wk,
                                const float* __restrict__ wv, u16* __restrict__ dst,
                                long long wz, long long dz) {
  __shared__ float t[32][33];
  int n0 = blockIdx.x * 32, k0 = blockIdx.y * 32;
  int which = n0 / 768;
  int r0 = n0 % 768;
  int h = r0 >> 6, e0 = r0 & 63;
  const float* src = which == 0 ? wq : (which == 1 ? wk : wv);
  src += (size_t)blockIdx.z * wz;
  dst += (size_t)blockIdx.z * dz;
  int tid = threadIdx.x;
  int tx = tid & 31, ty = tid >> 5;
  for (int r = ty; r < 32; r += 8) t[r][tx] = src[(size_t)(h * 768 + k0 + r) * 64 + e0 + tx];
  __syncthreads();
  for (int r = ty; r < 32; r += 8) dst[(size_t)(n0 + r) * 768 + k0 + tx] = f2bf(t[tx][r]);
}

// ---------------------------------------------------------------------------
// v [bh][s][e] -> vt [bh][e][s]
// ---------------------------------------------------------------------------
__global__ void transpose_v_kernel(const u16* __restrict__ v, u16* __restrict__ vt) {
  __shared__ u16 t[64][72];
  int bh = blockIdx.x, sc = blockIdx.y;
  int tid = threadIdx.x;
  const u16* src = v + ((size_t)bh * 1024 + sc * 64) * 64;
  int sl = tid >> 2, e0 = (tid & 3) * 16;
  ushort8v a = *(const ushort8v*)(src + (size_t)sl * 64 + e0);
  ushort8v b = *(const ushort8v*)(src + (size_t)sl * 64 + e0 + 8);
  #pragma unroll
  for (int j = 0; j < 8; ++j) t[sl][e0 + j] = a[j];
  #pragma unroll
  for (int j = 0; j < 8; ++j) t[sl][e0 + 8 + j] = b[j];
  __syncthreads();
  int e = tid >> 2, s0 = (tid & 3) * 16;
  ushort8v o0, o1;
  #pragma unroll
  for (int j = 0; j < 8; ++j) o0[j] = t[s0 + j][e];
  #pragma unroll
  for (int j = 0; j < 8; ++j) o1[j] = t[s0 + 8 + j][e];
  u16* dst = vt + ((size_t)bh * 64 + e) * 1024 + sc * 64 + s0;
  *(ushort8v*)dst = o0;
  *(ushort8v*)(dst + 8) = o1;
}

// ---------------------------------------------------------------------------
// gemm128 (proven round-2 structure): C[M,N] = A[M,K]*Wt[N,K], 128x128 tile,
// BK=64, 4 waves (wave tile 64x64), 2-barrier loop, global_load_lds width-16
// staging, both-sides XOR swizzle. Hoisted staging addresses; inner NK-step
// compile-time unroll x kOuter runtime chunks (bounds code size).
// No split-K, no atomics (proven regression in r5): one block per out tile.
// MODE 0: QKV scatter  MODE 1: xf += C  MODE 2: gelu(C+b1)->bf16  MODE 3: xf += C + b2
// ---------------------------------------------------------------------------
template <int MODE, int NK>
__global__ __launch_bounds__(256) void gemm128(
    const u16* __restrict__ A, int lda, const u16* __restrict__ Wt, int ldb, int kOuter,
    float* __restrict__ xf, u16* __restrict__ outb, const float* __restrict__ bias,
    u16* __restrict__ qb, u16* __restrict__ kb, u16* __restrict__ vb) {
  __shared__ alignas(16) u16 As[128 * 64];
  __shared__ alignas(16) u16 Bs[128 * 64];
  int tid = threadIdx.x, lane = tid & 63, w = tid >> 6;
  int wm = w >> 1, wn = w & 1;
  int m0 = blockIdx.x * 128, n0 = blockIdx.y * 128;
  f32x4 acc[4][4] = {};
  // staging addresses, hoisted: row r = i*32 + w*8 + lr, source 16B-slot cb^(lr<<4)
  int lr = lane >> 3;
  int cb = (lane & 7) << 4;
  int sws = cb ^ (lr << 4);
  const char* pA = (const char*)(A + (size_t)m0 * lda) + (size_t)(w * 8 + lr) * (lda * 2) + sws;
  const char* pB = (const char*)(Wt + (size_t)n0 * ldb) + (size_t)(w * 8 + lr) * (ldb * 2) + sws;
  char* dA = (char*)As + w * 1024;   // wave-uniform dest (+lane*16 implicit)
  char* dB = (char*)Bs + w * 1024;
  int arow = wm * 64 + (lane & 15);
  int brow = wn * 64 + (lane & 15);
  int e0 = (lane >> 4) * 8;
  for (int c = 0; c < kOuter; ++c) {
    #pragma unroll
    for (int kt = 0; kt < NK; ++kt) {
      __syncthreads();
      #pragma unroll
      for (int i = 0; i < 4; ++i) {
        __builtin_amdgcn_global_load_lds((gvoid_t*)(pA + (size_t)i * 32 * (lda * 2)),
                                         (lvoid_t*)(dA + i * 4096), 16, 0, 0);
        __builtin_amdgcn_global_load_lds((gvoid_t*)(pB + (size_t)i * 32 * (ldb * 2)),
                                         (lvoid_t*)(dB + i * 4096), 16, 0, 0);
      }
      pA += 128; pB += 128;
      __syncthreads();   // compiler emits vmcnt(0) drain here (staged data ready)
      #pragma unroll
      for (int kk = 0; kk < 2; ++kk) {
        bf16x8 af[4], bfr[4];
        #pragma unroll
        for (int mt = 0; mt < 4; ++mt) af[mt] = ldsfrag(As, arow + mt * 16, kk * 32 + e0);
        #pragma unroll
        for (int nt = 0; nt < 4; ++nt) bfr[nt] = ldsfrag(Bs, brow + nt * 16, kk * 32 + e0);
        #pragma unroll
        for (int mt = 0; mt < 4; ++mt)
          #pragma unroll
          for (int nt = 0; nt < 4; ++nt)
            acc[mt][nt] = MFMA(af[mt], bfr[nt], acc[mt][nt]);
      }
    }
  }
  int rbase = m0 + wm * 64 + ((lane >> 4) << 2);
  int cbase = n0 + wn * 64 + (lane & 15);
  if constexpr (MODE == 0) {
    int which = n0 / 768;
    u16* dstb = which == 0 ? qb : (which == 1 ? kb : vb);
    int cloc = cbase - which * 768;
    #pragma unroll
    for (int mt = 0; mt < 4; ++mt) {
      #pragma unroll
      for (int nt = 0; nt < 4; ++nt) {
        int rr = cloc + nt * 16;
        int h = rr >> 6, e = rr & 63;
        #pragma unroll
        for (int reg = 0; reg < 4; ++reg) {
          int row = rbase + mt * 16 + reg;
          int b = row >> 10, s = row & 1023;
          dstb[((size_t)(b * 12 + h) * 1024 + s) * 64 + e] = f2bf(acc[mt][nt][reg]);
        }
      }
    }
  } else if constexpr (MODE == 2) {
    #pragma unroll
    for (int mt = 0; mt < 4; ++mt) {
      #pragma unroll
      for (int nt = 0; nt < 4; ++nt) {
        int col = cbase + nt * 16;
        float bb = bias[col];
        #pragma unroll
        for (int reg = 0; reg < 4; ++reg) {
          int row = rbase + mt * 16 + reg;
          float t = acc[mt][nt][reg] + bb;
          float u = t * fmaf(t * t, 0.044715f, 1.0f);
          float ex = __builtin_amdgcn_exp2f(u * -2.3022156f);
          float g = t * __builtin_amdgcn_rcpf(1.0f + ex);
          outb[(size_t)row * 3072 + col] = f2bf(g);
        }
      }
    }
  } else {
    #pragma unroll
    for (int mt = 0; mt < 4; ++mt) {
      #pragma unroll
      for (int nt = 0; nt < 4; ++nt) {
        int col = cbase + nt * 16;
        float bb = (MODE == 3) ? bias[col] : 0.0f;
        #pragma unroll
        for (int reg = 0; reg < 4; ++reg) {
          int row = rbase + mt * 16 + reg;
          xf[(size_t)row * 768 + col] += acc[mt][nt][reg] + bb;
        }
      }
    }
  }
}

// ---------------------------------------------------------------------------
// flash attention, fixed-shift softmax (exact shift-invariance), l = P@ones
// via MFMA, double-buffered K/V staging (stage kt+1 lands during softmax/PV).
// q,k: [bh][s][64] ; vt: [bh][e][s] ; o: [b,s, h*64+e]
// ---------------------------------------------------------------------------
__global__ __launch_bounds__(256) void flash64(
    const u16* __restrict__ q, const u16* __restrict__ k, const u16* __restrict__ vt,
    const int* __restrict__ kmask, u16* __restrict__ o) {
  __shared__ alignas(16) u16 Qs[64 * 64];
  __shared__ alignas(16) u16 Ks[2][64 * 64];
  __shared__ alignas(16) u16 Vs[2][64 * 64];
  __shared__ alignas(16) u16 Ps[64 * 64];
  int tid = threadIdx.x, lane = tid & 63, w = tid >> 6;
  int lc = lane & 15;
  int bh = blockIdx.x, q0 = blockIdx.y * 64;
  int b = bh / 12, h = bh % 12;

  stage64(q + ((size_t)bh * 1024 + q0) * 64, 64, Qs, 64, tid);
  __syncthreads();
  int qrow = w * 16 + lc;
  int e0 = (lane >> 4) * 8;
  bf16x8 aq0 = ldsfrag(Qs, qrow, e0);
  bf16x8 aq1 = ldsfrag(Qs, qrow, 32 + e0);

  bf16x8 ones;
  #pragma unroll
  for (int j = 0; j < 8; ++j) ones[j] = (__bf16)1.0f;

  f32x4 oacc[4] = {};
  f32x4 lacc = {};
  const float SCL = 0.125f * 1.44269504f;
  const float SH = -3.0f * 1.44269504f;
  int prow_base = w * 16 + ((lane >> 4) << 2);

  stage64(k + (size_t)bh * 1024 * 64, 64, Ks[0], 64, tid);
  stage64(vt + (size_t)bh * 64 * 1024, 1024, Vs[0], 64, tid);

  for (int kt = 0; kt < 16; ++kt) {
    asm volatile("s_waitcnt vmcnt(0)" ::: "memory");
    __builtin_amdgcn_sched_barrier(0);
    __builtin_amdgcn_s_barrier();
    __builtin_amdgcn_sched_barrier(0);
    const u16* Kc = Ks[kt & 1];
    const u16* Vc = Vs[kt & 1];

    f32x4 sacc[4] = {};
    #pragma unroll
    for (int nt = 0; nt < 4; ++nt) {
      bf16x8 bk = ldsfrag(Kc, nt * 16 + lc, e0);
      sacc[nt] = MFMA(aq0, bk, sacc[nt]);
    }
    #pragma unroll
    for (int nt = 0; nt < 4; ++nt) {
      bf16x8 bk = ldsfrag(Kc, nt * 16 + lc, 32 + e0);
      sacc[nt] = MFMA(aq1, bk, sacc[nt]);
    }

    if (kt + 1 < 16) {
      stage64(k + ((size_t)bh * 1024 + (kt + 1) * 64) * 64, 64, Ks[(kt + 1) & 1], 64, tid);
      stage64(vt + (size_t)bh * 64 * 1024 + (kt + 1) * 64, 1024, Vs[(kt + 1) & 1], 64, tid);
    }

    #pragma unroll
    for (int nt = 0; nt < 4; ++nt) {
      int c = nt * 16 + lc;
      float mk = kmask[b * 1024 + kt * 64 + c] ? SH : -1e30f;
      #pragma unroll
      for (int r = 0; r < 4; ++r) {
        float p = __builtin_amdgcn_exp2f(fmaf(sacc[nt][r], SCL, mk));
        int prow = prow_base + r;
        int boff = prow * 128 + ((c << 1) ^ ((prow & 7) << 4));
        *(u16*)((char*)Ps + boff) = f2bf(p);
      }
    }

    bf16x8 ap0 = ldsfrag(Ps, qrow, e0);
    bf16x8 ap1 = ldsfrag(Ps, qrow, 32 + e0);
    lacc = MFMA(ap0, ones, lacc);
    lacc = MFMA(ap1, ones, lacc);
    #pragma unroll
    for (int et = 0; et < 4; ++et) {
      bf16x8 bv = ldsfrag(Vc, et * 16 + lc, e0);
      oacc[et] = MFMA(ap0, bv, oacc[et]);
    }
    #pragma unroll
    for (int et = 0; et < 4; ++et) {
      bf16x8 bv = ldsfrag(Vc, et * 16 + lc, 32 + e0);
      oacc[et] = MFMA(ap1, bv, oacc[et]);
    }
  }

  float rl[4];
  #pragma unroll
  for (int r = 0; r < 4; ++r) rl[r] = __builtin_amdgcn_rcpf(lacc[r]);
  int orow_base = q0 + prow_base;
  #pragma unroll
  for (int et = 0; et < 4; ++et) {
    int e = et * 16 + lc;
    #pragma unroll
    for (int r = 0; r < 4; ++r) {
      int row = orow_base + r;
      o[((size_t)(b * 1024 + row)) * 768 + h * 64 + e] = f2bf(oacc[et][r] * rl[r]);
    }
  }
}

__global__ void copy_kernel(const float* __restrict__ src, float* __restrict__ dst) {
  size_t i = (size_t)blockIdx.x * blockDim.x + threadIdx.x;
  ((float4v*)dst)[i] = ((const float4v*)src)[i];
}

// ---------------------------------------------------------------------------
extern "C" void kernel_launch(void* const* d_in, const int* in_sizes, int n_in,
                              void* d_out, int out_size, void* d_ws, size_t ws_size,
                              hipStream_t stream) {
  const int* tokens = (const int*)d_in[0];
  const int* kmask = (const int*)d_in[1];
  const float* emb = (const float*)d_in[2];
  const float* pe = (const float*)d_in[3];
  const float* ln1_s = (const float*)d_in[4];
  const float* ln1_b = (const float*)d_in[5];
  const float* wq = (const float*)d_in[6];
  const float* wk = (const float*)d_in[7];
  const float* wv = (const float*)d_in[8];
  const float* wo = (const float*)d_in[9];
  const float* ln2_s = (const float*)d_in[10];
  const float* ln2_b = (const float*)d_in[11];
  const float* w1 = (const float*)d_in[12];
  const float* b1 = (const float*)d_in[13];
  const float* w2 = (const float*)d_in[14];
  const float* b2 = (const float*)d_in[15];

  char* ws = (char*)d_ws;
  float* xf = (float*)ws;                       // 8192*768*4
  u16* xn   = (u16*)(ws + 25165824);
  u16* qb   = (u16*)(ws + 37748736);
  u16* kb   = (u16*)(ws + 50331648);
  u16* vb   = (u16*)(ws + 62914560);
  u16* vtb  = (u16*)(ws + 75497472);
  u16* ob   = (u16*)(ws + 88080384);
  u16* ffh  = (u16*)(ws + 100663296);           // 8192*3072*2

  const size_t SZ_QKV = (size_t)2304 * 768;
  const size_t SZ_O   = (size_t)768 * 768;
  const size_t SZ_F1  = (size_t)3072 * 768;
  const size_t SZ_F2  = (size_t)768 * 3072;
  const size_t NEED = 150994944 + 2 * 6 * (SZ_QKV + SZ_O + SZ_F1 + SZ_F2);
  bool pre = ws_size >= NEED;
  int nz = pre ? 6 : 1;
  u16* wqkvt = (u16*)(ws + 150994944);
  u16* wot   = wqkvt + (size_t)nz * SZ_QKV;
  u16* w1t   = wot + (size_t)nz * SZ_O;
  u16* w2t   = w1t + (size_t)nz * SZ_F1;

  embed_kernel<<<8192, 192, 0, stream>>>(tokens, emb, pe, xf);

  if (pre) {
    convqkvT_kernel<<<dim3(72, 24, 6), 256, 0, stream>>>(wq, wk, wv, wqkvt, 589824LL, (long long)SZ_QKV);
    convT_kernel<<<dim3(24, 24, 6), 256, 0, stream>>>(wo, wot, 768, 768, 589824LL, (long long)SZ_O);
    convT_kernel<<<dim3(96, 24, 6), 256, 0, stream>>>(w1, w1t, 3072, 768, 2359296LL, (long long)SZ_F1);
    convT_kernel<<<dim3(24, 96, 6), 256, 0, stream>>>(w2, w2t, 768, 3072, 2359296LL, (long long)SZ_F2);
  }

  for (int l = 0; l < 6; ++l) {
    size_t woff_qkv = (size_t)l * 12 * 768 * 64;
    size_t woff_o = (size_t)l * 768 * 768;
    size_t woff_ff = (size_t)l * 768 * 3072;
    const u16* wt_qkv_l = wqkvt + (pre ? (size_t)l * SZ_QKV : 0);
    const u16* wt_o_l   = wot   + (pre ? (size_t)l * SZ_O   : 0);
    const u16* wt_1_l   = w1t   + (pre ? (size_t)l * SZ_F1  : 0);
    const u16* wt_2_l   = w2t   + (pre ? (size_t)l * SZ_F2  : 0);

    if (!pre) {
      convqkvT_kernel<<<dim3(72, 24, 1), 256, 0, stream>>>(wq + woff_qkv, wk + woff_qkv, wv + woff_qkv, (u16*)wt_qkv_l, 0LL, 0LL);
      convT_kernel<<<dim3(24, 24, 1), 256, 0, stream>>>(wo + woff_o, (u16*)wt_o_l, 768, 768, 0LL, 0LL);
      convT_kernel<<<dim3(96, 24, 1), 256, 0, stream>>>(w1 + woff_ff, (u16*)wt_1_l, 3072, 768, 0LL, 0LL);
      convT_kernel<<<dim3(24, 96, 1), 256, 0, stream>>>(w2 + woff_ff, (u16*)wt_2_l, 768, 3072, 0LL, 0LL);
    }

    ln_kernel<<<8192, 192, 0, stream>>>(xf, ln1_s + l * 768, ln1_b + l * 768, xn);
    gemm128<0, 6><<<dim3(64, 18, 1), 256, 0, stream>>>(xn, 768, wt_qkv_l, 768, 2, nullptr, nullptr, nullptr, qb, kb, vb);
    transpose_v_kernel<<<dim3(96, 16), 256, 0, stream>>>(vb, vtb);
    flash64<<<dim3(96, 16), 256, 0, stream>>>(qb, kb, vtb, kmask, ob);
    gemm128<1, 6><<<dim3(64, 6, 1), 256, 0, stream>>>(ob, 768, wt_o_l, 768, 2, xf, nullptr, nullptr, nullptr, nullptr, nullptr);
    ln_kernel<<<8192, 192, 0, stream>>>(xf, ln2_s + l * 768, ln2_b + l * 768, xn);
    gemm128<2, 6><<<dim3(64, 24, 1), 256, 0, stream>>>(xn, 768, wt_1_l, 768, 2, nullptr, ffh, b1 + l * 3072, nullptr, nullptr, nullptr);
    gemm128<3, 6><<<dim3(64, 6, 1), 256, 0, stream>>>(ffh, 3072, wt_2_l, 3072, 8, xf, nullptr, b2 + l * 768, nullptr, nullptr, nullptr);
  }

  copy_kernel<<<6144, 256, 0, stream>>>(xf, (float*)d_out);
}